// Round 8
// baseline (3397.329 us; speedup 1.0000x reference)
//
#include <hip/hip_runtime.h>
#include <cstddef>

#define B_ 64
#define T_ 32
#define S_ 128
#define IN_ 1024
#define H_ 1024

typedef __bf16 bf16x8 __attribute__((ext_vector_type(8)));
typedef float f32x4 __attribute__((ext_vector_type(4)));

__device__ __forceinline__ float sigmoidf_(float x) { return 1.0f / (1.0f + expf(-x)); }

__device__ __forceinline__ ushort f2bf(float x) {
    unsigned u = __builtin_bit_cast(unsigned, x);
    unsigned r = (u + 0x7fffu + ((u >> 16) & 1u)) >> 16;
    return (ushort)r;
}
__device__ __forceinline__ float bf2f(ushort h) {
    unsigned u = ((unsigned)h) << 16;
    return __builtin_bit_cast(float, u);
}

// async global->LDS, 16B per lane; lds dest wave-uniform (HW adds lane*16).
__device__ __forceinline__ void gll16(const ushort* g, ushort* l) {
    __builtin_amdgcn_global_load_lds(
        (const __attribute__((address_space(1))) void*)g,
        (__attribute__((address_space(3))) void*)l,
        16, 0, 0);
}

// 64-block group barrier. fence(agent) -> L2 writeback; acquire -> L2 inv, so
// cross-XCD visibility is handled (CG grid-sync pattern).
__device__ __forceinline__ void gbar(unsigned* cnt, unsigned* gen) {
    __syncthreads();
    if (threadIdx.x == 0) {
        __threadfence();
        unsigned g = __hip_atomic_load(gen, __ATOMIC_RELAXED, __HIP_MEMORY_SCOPE_AGENT);
        unsigned a = __hip_atomic_fetch_add(cnt, 1u, __ATOMIC_ACQ_REL, __HIP_MEMORY_SCOPE_AGENT);
        if (a == 63u) {
            __hip_atomic_store(cnt, 0u, __ATOMIC_RELAXED, __HIP_MEMORY_SCOPE_AGENT);
            __hip_atomic_store(gen, g + 1u, __ATOMIC_RELEASE, __HIP_MEMORY_SCOPE_AGENT);
        } else {
            while (__hip_atomic_load(gen, __ATOMIC_ACQUIRE, __HIP_MEMORY_SCOPE_AGENT) == g)
                __builtin_amdgcn_s_sleep(2);
        }
    }
    __syncthreads();
}

// ---------------- big-GEMM (preamble): C = A @ B^T, split-bf16 planes ----------
template<int FM, int FN, bool ALO, bool BLO>
__global__ __launch_bounds__(256) void gemm_bf(
    const ushort* __restrict__ Ah_g, const ushort* __restrict__ Al_g, long lda,
    const ushort* __restrict__ Bh_g, const ushort* __restrict__ Bl_g, long ldb,
    int K, int N,
    float* __restrict__ Cf, ushort* __restrict__ Cbh, ushort* __restrict__ Cbl,
    const float* __restrict__ bias,
    long Az, long Bz, long Cz)
{
    constexpr int NSA = 4 * FM;
    constexpr int NSB = 4 * FN;
    constexpr int OAL = NSA;
    constexpr int OBH = NSA * (ALO ? 2 : 1);
    constexpr int OBL = OBH + NSB;
    constexpr int NST = OBH + NSB * (BLO ? 2 : 1);
    __shared__ ushort lds[NST * 512];

    const long z = blockIdx.z;
    Ah_g += z * Az; if (ALO) Al_g += z * Az;
    Bh_g += z * Bz; if (BLO) Bl_g += z * Bz;
    if (Cf) Cf += z * Cz;
    if (Cbh) Cbh += z * Cz;
    if (Cbl) Cbl += z * Cz;

    const int tid = threadIdx.x;
    const int lane = tid & 63, wv = tid >> 6;
    const int wm = wv >> 1, wn = wv & 1;
    const int m0 = blockIdx.y * (FM * 32), n0 = blockIdx.x * (FN * 32);
    const int lr = lane & 15, lc = lane >> 4;

    f32x4 acc[FM][FN];
#pragma unroll
    for (int i = 0; i < FM; ++i)
#pragma unroll
        for (int j = 0; j < FN; ++j) acc[i][j] = (f32x4){0.f, 0.f, 0.f, 0.f};

    for (int k0 = 0; k0 < K; k0 += 64) {
#pragma unroll
        for (int q = 0; q < NST / 4; ++q) {
            const int si = wv * (NST / 4) + q;
            const ushort* P; long ld; int row0; int st;
            if (si < OBH) {
                if (ALO && si >= NSA) { P = Al_g; st = si - NSA; }
                else                  { P = Ah_g; st = si; }
                ld = lda; row0 = m0;
            } else {
                const int sj = si - OBH;
                if (BLO && sj >= NSB) { P = Bl_g; st = sj - NSB; }
                else                  { P = Bh_g; st = sj; }
                ld = ldb; row0 = n0;
            }
            const int row = ((st >> 1) << 4) + lr;
            const int kc = ((st & 1) << 5) + (lc << 3);
            gll16(P + (size_t)(row0 + row) * ld + k0 + kc, &lds[si * 512]);
        }
        __syncthreads();
#pragma unroll
        for (int ks = 0; ks < 2; ++ks) {
            bf16x8 ah[FM], al[FM], bh[FN], bl[FN];
#pragma unroll
            for (int i = 0; i < FM; ++i) {
                const int st = (wm * FM + i) * 2 + ks;
                ah[i] = *(const bf16x8*)&lds[st * 512 + lane * 8];
                if (ALO) al[i] = *(const bf16x8*)&lds[(OAL + st) * 512 + lane * 8];
            }
#pragma unroll
            for (int j = 0; j < FN; ++j) {
                const int st = (wn * FN + j) * 2 + ks;
                bh[j] = *(const bf16x8*)&lds[(OBH + st) * 512 + lane * 8];
                if (BLO) bl[j] = *(const bf16x8*)&lds[(OBL + st) * 512 + lane * 8];
            }
#pragma unroll
            for (int i = 0; i < FM; ++i)
#pragma unroll
                for (int j = 0; j < FN; ++j) {
                    acc[i][j] = __builtin_amdgcn_mfma_f32_16x16x32_bf16(ah[i], bh[j], acc[i][j], 0, 0, 0);
                    if (BLO) acc[i][j] = __builtin_amdgcn_mfma_f32_16x16x32_bf16(ah[i], bl[j], acc[i][j], 0, 0, 0);
                    if (ALO) acc[i][j] = __builtin_amdgcn_mfma_f32_16x16x32_bf16(al[i], bh[j], acc[i][j], 0, 0, 0);
                }
        }
        __syncthreads();
    }

    const int fr = lane & 15, fc = lane >> 4;
#pragma unroll
    for (int i = 0; i < FM; ++i)
#pragma unroll
        for (int j = 0; j < FN; ++j) {
            const int mb = m0 + wm * FM * 16 + i * 16 + fc * 4;
            const int nb = n0 + wn * FN * 16 + j * 16 + fr;
            const float bv = bias ? bias[nb] : 0.f;
#pragma unroll
            for (int r = 0; r < 4; ++r) {
                const float v = acc[i][j][r] + bv;
                const size_t o = (size_t)(mb + r) * N + nb;
                if (Cf) Cf[o] = v;
                else if (Cbl) { const ushort hh = f2bf(v); Cbh[o] = hh; Cbl[o] = f2bf(v - bf2f(hh)); }
                else Cbh[o] = f2bf(v);
            }
        }
}

// ---------------- persistent loop helpers ----------------

__device__ __forceinline__ void gc_issue(
    const ushort* __restrict__ hc_h, const ushort* __restrict__ hc_l,
    const ushort* __restrict__ Whh_h, const ushort* __restrict__ Whh_l,
    int jc, int mb, int wv, int lr, int lc, int k0, ushort* dst)
{
#pragma unroll
    for (int q = 0; q < 5; ++q) {
        const int si = wv * 5 + q;
        const ushort* P; size_t rowoff; int ks;
        if (si < 4) {
            P = (si < 2) ? hc_h : hc_l;
            ks = si & 1;
            rowoff = (size_t)(mb * 16 + lr) * 1024;
        } else {
            const int sj = si - 4;
            P = (sj < 8) ? Whh_h : Whh_l;
            const int g = (sj & 7) >> 1;
            ks = sj & 1;
            rowoff = (size_t)(g * 1024 + jc * 16 + lr) * 1024;
        }
        gll16(P + rowoff + k0 + ks * 32 + lc * 8, dst + si * 512);
    }
}

__device__ __forceinline__ void og_issue(
    const ushort* __restrict__ hy_h, const ushort* __restrict__ hy_l,
    const ushort* __restrict__ Woi_h, const ushort* __restrict__ Woi_l,
    size_t arow, size_t brow, int kb, int it, int lc, ushort* dst)
{
    const int k0 = kb + it * 64 + lc * 8;
    gll16(hy_h + arow + k0,       dst);
    gll16(hy_h + arow + k0 + 32,  dst + 512);
    gll16(hy_l + arow + k0,       dst + 1024);
    gll16(hy_l + arow + k0 + 32,  dst + 1536);
    gll16(Woi_h + brow + k0,      dst + 2048);
    gll16(Woi_h + brow + k0 + 32, dst + 2560);
    gll16(Woi_l + brow + k0,      dst + 3072);
    gll16(Woi_l + brow + k0 + 32, dst + 3584);
}

// Persistent T-loop. 256 blocks = 4 groups x 64. Group g owns batches g*16..+15.
// Per step: A gates+cell -> bar -> B scores -> bar -> C out+h -> bar.
__global__ __launch_bounds__(256, 1) void loop_k(
    const ushort* __restrict__ Whh_h, const ushort* __restrict__ Whh_l,
    const float* __restrict__ xW,
    const float* __restrict__ c0, float* __restrict__ cT,
    ushort* __restrict__ hy_h, ushort* __restrict__ hy_l,
    ushort* __restrict__ hc_h, ushort* __restrict__ hc_l,
    const float* __restrict__ E, const float* __restrict__ mask,
    float* __restrict__ sc_raw,
    const float* __restrict__ Gtf,
    const ushort* __restrict__ Woi_h, const ushort* __restrict__ Woi_l,
    float* __restrict__ outp, float* __restrict__ hT,
    unsigned* __restrict__ bar)
{
    __shared__ __align__(16) char smraw[77824];
    const int bid = blockIdx.x;
    const int mb = bid >> 6, xb = bid & 63;
    const int tid = threadIdx.x, lane = tid & 63, wv = tid >> 6;
    const int lr = lane & 15, lc = lane >> 4;
    const int fr = lane & 15, fc = lane >> 4;
    const int bl_ = tid >> 4, tl = tid & 15;

    unsigned* cnt = bar + mb * 64;
    unsigned* gen = bar + mb * 64 + 32;

    const int eb = mb * 16 + bl_;       // this thread's batch (phase A & C epilogues)
    const int ecol = xb * 16 + tl;      // this thread's column
    const int eidx = eb * 1024 + ecol;
    float creg = c0[eidx];

    const int s_batch = mb * 16 + (xb & 15);
    const int s_sg = xb >> 4;

#pragma unroll 1
    for (int t = 0; t < T_; ++t) {
        // ================= phase A: gates + LSTM cell =================
        {
            ushort (*lds3)[10240] = (ushort (*)[10240])smraw;   // 60 KB (3 bufs)
            float* gl = (float*)(smraw + 61440);                // 4 KB
            f32x4 acc = (f32x4){0.f, 0.f, 0.f, 0.f};
            gc_issue(hc_h, hc_l, Whh_h, Whh_l, xb, mb, wv, lr, lc, 0, lds3[0]);
#pragma unroll
            for (int it = 0; it < 16; ++it) {
                if (it < 15) {
                    gc_issue(hc_h, hc_l, Whh_h, Whh_l, xb, mb, wv, lr, lc,
                             (it + 1) * 64, lds3[(it + 1) % 3]);
                    asm volatile("s_waitcnt vmcnt(5)" ::: "memory");
                } else {
                    asm volatile("s_waitcnt vmcnt(0)" ::: "memory");
                }
                __builtin_amdgcn_s_barrier();
                __builtin_amdgcn_sched_barrier(0);
                const ushort* L = lds3[it % 3];
#pragma unroll
                for (int ks = 0; ks < 2; ++ks) {
                    bf16x8 ah = *(const bf16x8*)&L[ks * 512 + lane * 8];
                    bf16x8 al = *(const bf16x8*)&L[(2 + ks) * 512 + lane * 8];
                    bf16x8 bh = *(const bf16x8*)&L[(4 + wv * 2 + ks) * 512 + lane * 8];
                    bf16x8 bl = *(const bf16x8*)&L[(12 + wv * 2 + ks) * 512 + lane * 8];
                    acc = __builtin_amdgcn_mfma_f32_16x16x32_bf16(ah, bh, acc, 0, 0, 0);
                    acc = __builtin_amdgcn_mfma_f32_16x16x32_bf16(ah, bl, acc, 0, 0, 0);
                    acc = __builtin_amdgcn_mfma_f32_16x16x32_bf16(al, bh, acc, 0, 0, 0);
                }
            }
#pragma unroll
            for (int r = 0; r < 4; ++r)
                gl[wv * 256 + (fc * 4 + r) * 16 + fr] = acc[r];
            __syncthreads();

            const float* xw = xW + ((size_t)eb * T_ + t) * 4096;
            const float gi = gl[bl_ * 16 + tl]        + xw[ecol];
            const float gf = gl[256 + bl_ * 16 + tl]  + xw[1024 + ecol];
            const float gg = gl[512 + bl_ * 16 + tl]  + xw[2048 + ecol];
            const float go = gl[768 + bl_ * 16 + tl]  + xw[3072 + ecol];
            creg = sigmoidf_(gf) * creg + sigmoidf_(gi) * tanhf(gg);
            const float h = sigmoidf_(go) * tanhf(creg);
            const ushort hh = f2bf(h);
            hy_h[eidx] = hh;
            hy_l[eidx] = f2bf(h - bf2f(hh));
        }
        gbar(cnt, gen);

        // ================= phase B: raw scores =================
        {
            float* sinp = (float*)smraw;   // 4 KB
            {
                const ushort4 h4 = *(const ushort4*)(hy_h + (size_t)s_batch * 1024 + tid * 4);
                const ushort4 l4 = *(const ushort4*)(hy_l + (size_t)s_batch * 1024 + tid * 4);
                sinp[tid * 4 + 0] = bf2f(h4.x) + bf2f(l4.x);
                sinp[tid * 4 + 1] = bf2f(h4.y) + bf2f(l4.y);
                sinp[tid * 4 + 2] = bf2f(h4.z) + bf2f(l4.z);
                sinp[tid * 4 + 3] = bf2f(h4.w) + bf2f(l4.w);
            }
            __syncthreads();
            const float4* s4 = (const float4*)sinp;
#pragma unroll
            for (int r = 0; r < 8; ++r) {
                const int s = s_sg * 32 + wv * 8 + r;
                const float4* row = (const float4*)(E + ((size_t)s_batch * S_ + s) * 1024);
                float sum = 0.f;
#pragma unroll
                for (int i = 0; i < 4; ++i) {
                    const float4 v = row[lane + i * 64];
                    const float4 w = s4[lane + i * 64];
                    sum += v.x * w.x + v.y * w.y + v.z * w.z + v.w * w.w;
                }
#pragma unroll
                for (int off = 32; off > 0; off >>= 1) sum += __shfl_xor(sum, off);
                if (lane == 0)
                    sc_raw[s_batch * S_ + s] = sum - (1.0f - mask[(size_t)s_batch * S_ + s]) * 100000.0f;
            }
        }
        gbar(cnt, gen);

        // ================= phase C: out = tanh(softmax@Gt + hy@Woi^T) =================
        {
            ushort* st = (ushort*)smraw;                          // 64 KB: [4][2][4096]
            float (*aS)[128] = (float (*)[128])(smraw + 65536);   // 8 KB
            float* red = (float*)(smraw + 73728);                 // 4 KB
            const int kb = wv * 256;
            const size_t arow = (size_t)(mb * 16 + lr) * 1024;
            const size_t brow = (size_t)(xb * 16 + lr) * 1024;
            ushort* stw = st + wv * 8192;
            og_issue(hy_h, hy_l, Woi_h, Woi_l, arow, brow, kb, 0, lc, stw);

            // softmax for 16 batches (16-lane groups)
            float v[8], mx = -3.4e38f;
#pragma unroll
            for (int i = 0; i < 8; ++i) {
                v[i] = sc_raw[eb * S_ + tl * 8 + i];
                mx = fmaxf(mx, v[i]);
            }
#pragma unroll
            for (int off = 1; off < 16; off <<= 1) mx = fmaxf(mx, __shfl_xor(mx, off));
            float sm = 0.f;
#pragma unroll
            for (int i = 0; i < 8; ++i) { v[i] = expf(v[i] - mx); sm += v[i]; }
#pragma unroll
            for (int off = 1; off < 16; off <<= 1) sm += __shfl_xor(sm, off);
            const float inv = 1.0f / sm;
#pragma unroll
            for (int i = 0; i < 8; ++i) aS[bl_][tl * 8 + i] = v[i] * inv;
            asm volatile("s_waitcnt lgkmcnt(0)" ::: "memory");

            // G part: a @ Gt[b][col][:]
            const float* gt = Gtf + ((size_t)eb * 1024 + ecol) * 128;
            float accg = 0.f;
#pragma unroll
            for (int i = 0; i < 32; ++i) {
                const float4 g4 = *(const float4*)(gt + i * 4);
                const float* a = &aS[bl_][i * 4];
                accg += a[0] * g4.x + a[1] * g4.y + a[2] * g4.z + a[3] * g4.w;
            }

            // MFMA part: hy @ Woi^T, wave-private K slice, dbuf counted vmcnt
            asm volatile("s_waitcnt vmcnt(0)" ::: "memory");
            f32x4 acc = (f32x4){0.f, 0.f, 0.f, 0.f};
#pragma unroll
            for (int it = 0; it < 4; ++it) {
                if (it < 3) {
                    og_issue(hy_h, hy_l, Woi_h, Woi_l, arow, brow, kb, it + 1, lc,
                             stw + ((it + 1) & 1) * 4096);
                    asm volatile("s_waitcnt vmcnt(8)" ::: "memory");
                } else {
                    asm volatile("s_waitcnt vmcnt(0)" ::: "memory");
                }
                __builtin_amdgcn_sched_barrier(0);
                const ushort* W = stw + (it & 1) * 4096;
#pragma unroll
                for (int ks = 0; ks < 2; ++ks) {
                    bf16x8 ah = *(const bf16x8*)&W[ks * 512 + lane * 8];
                    bf16x8 al = *(const bf16x8*)&W[(2 + ks) * 512 + lane * 8];
                    bf16x8 bh = *(const bf16x8*)&W[(4 + ks) * 512 + lane * 8];
                    bf16x8 bl = *(const bf16x8*)&W[(6 + ks) * 512 + lane * 8];
                    acc = __builtin_amdgcn_mfma_f32_16x16x32_bf16(ah, bh, acc, 0, 0, 0);
                    acc = __builtin_amdgcn_mfma_f32_16x16x32_bf16(ah, bl, acc, 0, 0, 0);
                    acc = __builtin_amdgcn_mfma_f32_16x16x32_bf16(al, bh, acc, 0, 0, 0);
                }
            }
#pragma unroll
            for (int r = 0; r < 4; ++r)
                red[wv * 256 + (fc * 4 + r) * 16 + fr] = acc[r];
            __syncthreads();

            float o = accg + red[bl_ * 16 + tl] + red[256 + bl_ * 16 + tl]
                    + red[512 + bl_ * 16 + tl] + red[768 + bl_ * 16 + tl];
            o = tanhf(o);
            outp[((size_t)eb * T_ + t) * 1024 + ecol] = o;
            const ushort hh2 = f2bf(o);
            hc_h[eidx] = hh2;
            hc_l[eidx] = f2bf(o - bf2f(hh2));
            if (t == T_ - 1) hT[eidx] = o;
        }
        gbar(cnt, gen);
    }
    cT[eidx] = creg;
}

// ---------------- conversion / misc ----------------
__global__ __launch_bounds__(256) void cvt2_k(
    const float* __restrict__ in, ushort* __restrict__ hi, ushort* __restrict__ lo, int n4)
{
    const int i = blockIdx.x * 256 + threadIdx.x;
    if (i >= n4) return;
    const float4 v = ((const float4*)in)[i];
    ushort4 h, l;
    h.x = f2bf(v.x); l.x = f2bf(v.x - bf2f(h.x));
    h.y = f2bf(v.y); l.y = f2bf(v.y - bf2f(h.y));
    h.z = f2bf(v.z); l.z = f2bf(v.z - bf2f(h.z));
    h.w = f2bf(v.w); l.w = f2bf(v.w - bf2f(h.w));
    ((ushort4*)hi)[i] = h;
    ((ushort4*)lo)[i] = l;
}

__global__ __launch_bounds__(256) void cvt1_k(
    const float* __restrict__ in, ushort* __restrict__ hi, int n4)
{
    const int i = blockIdx.x * 256 + threadIdx.x;
    if (i >= n4) return;
    const float4 v = ((const float4*)in)[i];
    ushort4 h;
    h.x = f2bf(v.x); h.y = f2bf(v.y); h.z = f2bf(v.z); h.w = f2bf(v.w);
    ((ushort4*)hi)[i] = h;
}

__global__ __launch_bounds__(256) void cvt2s_k(
    const float* __restrict__ in, long instride4, int rowlen4,
    ushort* __restrict__ hi, ushort* __restrict__ lo, int n4)
{
    const int i = blockIdx.x * 256 + threadIdx.x;
    if (i >= n4) return;
    const int r = i / rowlen4, c = i - r * rowlen4;
    const float4 v = ((const float4*)in)[(size_t)r * instride4 + c];
    ushort4 h, l;
    h.x = f2bf(v.x); l.x = f2bf(v.x - bf2f(h.x));
    h.y = f2bf(v.y); l.y = f2bf(v.y - bf2f(h.y));
    h.z = f2bf(v.z); l.z = f2bf(v.z - bf2f(h.z));
    h.w = f2bf(v.w); l.w = f2bf(v.w - bf2f(h.w));
    ((ushort4*)hi)[i] = h;
    ((ushort4*)lo)[i] = l;
}

__global__ void transpose_k(const float* __restrict__ in, float* __restrict__ out)
{
    __shared__ float tile[32][33];
    const int bx = blockIdx.x * 32, by = blockIdx.y * 32;
    const int tx = threadIdx.x, ty = threadIdx.y;   // (32,8)
#pragma unroll
    for (int i = 0; i < 32; i += 8)
        tile[ty + i][tx] = in[(size_t)(by + ty + i) * 1024 + bx + tx];
    __syncthreads();
#pragma unroll
    for (int i = 0; i < 32; i += 8)
        out[(size_t)(bx + ty + i) * 1024 + by + tx] = tile[tx][ty + i];
}

__global__ __launch_bounds__(256) void add_bias_k(
    const float* __restrict__ a, const float* __restrict__ b, float* __restrict__ o, int n)
{
    const int i = blockIdx.x * 256 + threadIdx.x;
    if (i < n) o[i] = a[i] + b[i];
}

extern "C" void kernel_launch(void* const* d_in, const int* in_sizes, int n_in,
                              void* d_out, int out_size, void* d_ws, size_t ws_size,
                              hipStream_t stream) {
    const float* target = (const float*)d_in[0];
    const float* h0     = (const float*)d_in[1];
    const float* c0     = (const float*)d_in[2];
    const float* ctx    = (const float*)d_in[3];
    const float* mask   = (const float*)d_in[4];
    const float* W_ih   = (const float*)d_in[5];
    const float* b_ih   = (const float*)d_in[6];
    const float* W_hh   = (const float*)d_in[7];
    const float* b_hh   = (const float*)d_in[8];
    const float* W_in   = (const float*)d_in[9];
    const float* W_ctx  = (const float*)d_in[10];
    const float* W_out  = (const float*)d_in[11];

    float* out = (float*)d_out;
    float* hT  = out + (size_t)B_ * T_ * H_;
    float* cT  = hT + (size_t)B_ * H_;

    // ---- workspace layout ----
    char* p = (char*)d_ws;
    float*  E     = (float*)p;             p += 8388608ull * 4;    // 33.55 MB (hosts ctx_h first)
    float*  xW    = (float*)p;             p += 8388608ull * 4;    // 33.55 MB
    float*  Gtf   = (float*)p;             p += 8388608ull * 4;    // 33.55 MB fp32
    ushort* Whh_h = (ushort*)p;            p += 4194304ull * 2;
    ushort* Whh_l = (ushort*)p;            p += 4194304ull * 2;
    ushort* Woi_h = (ushort*)p;            p += 1048576ull * 2;
    ushort* Woi_l = (ushort*)p;            p += 1048576ull * 2;
    float*  bias_sum = (float*)p;          p += 4096ull * 4;
    unsigned* bar = (unsigned*)p;          p += 1024;              // 4 groups x (cnt,gen)
    ushort* hy_h  = (ushort*)p;            p += 65536ull * 2;
    ushort* hy_l  = (ushort*)p;            p += 65536ull * 2;
    ushort* hc_h  = (ushort*)p;            p += 65536ull * 2;
    ushort* hc_l  = (ushort*)p;            p += 65536ull * 2;
    float*  sc_raw = (float*)p;            p += 8192ull * 4;
    ushort* dcslot = (ushort*)p;           p += 8388608ull * 2;    // dc_b, later tgt planes
    ushort* trans  = (ushort*)p;           p += 8388608ull * 2;    // shared transient

    ushort* ctx_h  = (ushort*)E;           // ctx bf16 in E slot (dead before E written)
    ushort* dc_b   = dcslot;
    // transient phase A: W_ctx planes
    ushort* Wctx_h = trans;
    ushort* Wctx_l = trans + 2097152;
    // transient phase B: WinT + Wo1 + Wo2 planes + WinT_f
    ushort* WinT_h = trans;
    ushort* WinT_l = trans + 1048576;
    ushort* Wo1_h  = trans + 2097152;
    ushort* Wo1_l  = trans + 3145728;
    ushort* Wo2_h  = trans + 4194304;
    ushort* Wo2_l  = trans + 5242880;
    float*  WinT_f = (float*)(trans + 6291456);
    // transient phase C: target planes (dc slot) + W_ih planes (trans)
    ushort* tgt_h  = dcslot;
    ushort* tgt_l  = dcslot + 2097152;
    ushort* Wih_h  = trans;
    ushort* Wih_l  = trans + 4194304;

    // ---- preamble ----
    hipMemsetAsync(bar, 0, 1024, stream);
    add_bias_k<<<16, 256, 0, stream>>>(b_ih, b_hh, bias_sum, 4 * H_);
    cvt2_k<<<4096, 256, 0, stream>>>(W_hh, Whh_h, Whh_l, 1048576);

    // dense_ctx (bf16) = ctx @ W_ctx^T
    cvt1_k<<<16384, 256, 0, stream>>>(ctx, ctx_h, 4194304);
    cvt2_k<<<2048, 256, 0, stream>>>(W_ctx, Wctx_h, Wctx_l, 524288);
    gemm_bf<4, 4, false, true><<<dim3(8, 64), 256, 0, stream>>>(
        ctx_h, nullptr, 2048, Wctx_h, Wctx_l, 2048,
        2048, 1024, nullptr, dc_b, nullptr, nullptr, 0, 0, 0);

    // WinT, Woi = Wo2@W_in, E = dc@W_in, Gtf[b] = Wo1 @ dc[b]^T (fp32)
    transpose_k<<<dim3(32, 32), dim3(32, 8), 0, stream>>>(W_in, WinT_f);
    cvt2_k<<<1024, 256, 0, stream>>>(WinT_f, WinT_h, WinT_l, 262144);
    cvt2s_k<<<1024, 256, 0, stream>>>(W_out, 512, 256, Wo1_h, Wo1_l, 262144);
    cvt2s_k<<<1024, 256, 0, stream>>>(W_out + 1024, 512, 256, Wo2_h, Wo2_l, 262144);
    gemm_bf<4, 4, true, true><<<dim3(8, 8), 256, 0, stream>>>(
        Wo2_h, Wo2_l, 1024, WinT_h, WinT_l, 1024,
        1024, 1024, nullptr, Woi_h, Woi_l, nullptr, 0, 0, 0);
    gemm_bf<4, 4, false, true><<<dim3(8, 64), 256, 0, stream>>>(
        dc_b, nullptr, 1024, WinT_h, WinT_l, 1024,
        1024, 1024, E, nullptr, nullptr, nullptr, 0, 0, 0);
    gemm_bf<4, 4, true, false><<<dim3(1, 8, 64), 256, 0, stream>>>(
        Wo1_h, Wo1_l, 1024, dc_b, nullptr, 1024,
        1024, 128, Gtf, nullptr, nullptr, nullptr, 0, 131072, 131072);

    // xW = target @ W_ih^T + bias (dc dead now)
    cvt2_k<<<2048, 256, 0, stream>>>(target, tgt_h, tgt_l, 524288);
    cvt2_k<<<4096, 256, 0, stream>>>(W_ih, Wih_h, Wih_l, 1048576);
    gemm_bf<4, 4, true, true><<<dim3(32, 16), 256, 0, stream>>>(
        tgt_h, tgt_l, 1024, Wih_h, Wih_l, 1024,
        1024, 4096, xW, nullptr, nullptr, bias_sum, 0, 0, 0);

    // loop state: h0 planes
    cvt2_k<<<64, 256, 0, stream>>>(h0, hc_h, hc_l, 16384);

    // persistent T-loop (one launch)
    loop_k<<<256, 256, 0, stream>>>(
        Whh_h, Whh_l, xW, c0, cT, hy_h, hy_l, hc_h, hc_l,
        E, mask, sc_raw, Gtf, Woi_h, Woi_l, out, hT, bar);
}

// Round 9
// 1771.010 us; speedup vs baseline: 1.9183x; 1.9183x over previous
//
#include <hip/hip_runtime.h>
#include <cstddef>

#define B_ 64
#define T_ 32
#define S_ 128
#define IN_ 1024
#define H_ 1024

typedef __bf16 bf16x8 __attribute__((ext_vector_type(8)));
typedef float f32x4 __attribute__((ext_vector_type(4)));

__device__ __forceinline__ float sigmoidf_(float x) { return 1.0f / (1.0f + expf(-x)); }

__device__ __forceinline__ ushort f2bf(float x) {
    unsigned u = __builtin_bit_cast(unsigned, x);
    unsigned r = (u + 0x7fffu + ((u >> 16) & 1u)) >> 16;
    return (ushort)r;
}
__device__ __forceinline__ float bf2f(ushort h) {
    unsigned u = ((unsigned)h) << 16;
    return __builtin_bit_cast(float, u);
}

// async global->LDS, 16B per lane; lds dest wave-uniform (HW adds lane*16).
__device__ __forceinline__ void gll16(const ushort* g, ushort* l) {
    __builtin_amdgcn_global_load_lds(
        (const __attribute__((address_space(1))) void*)g,
        (__attribute__((address_space(3))) void*)l,
        16, 0, 0);
}

// ---------------- big-GEMM (preamble): C = A @ B^T, split-bf16 planes ----------
template<int FM, int FN, bool ALO, bool BLO>
__global__ __launch_bounds__(256) void gemm_bf(
    const ushort* __restrict__ Ah_g, const ushort* __restrict__ Al_g, long lda,
    const ushort* __restrict__ Bh_g, const ushort* __restrict__ Bl_g, long ldb,
    int K, int N,
    float* __restrict__ Cf, ushort* __restrict__ Cbh, ushort* __restrict__ Cbl,
    const float* __restrict__ bias)
{
    constexpr int NSA = 4 * FM;
    constexpr int NSB = 4 * FN;
    constexpr int OAL = NSA;
    constexpr int OBH = NSA * (ALO ? 2 : 1);
    constexpr int OBL = OBH + NSB;
    constexpr int NST = OBH + NSB * (BLO ? 2 : 1);
    __shared__ ushort lds[NST * 512];

    const int tid = threadIdx.x;
    const int lane = tid & 63, wv = tid >> 6;
    const int wm = wv >> 1, wn = wv & 1;
    const int m0 = blockIdx.y * (FM * 32), n0 = blockIdx.x * (FN * 32);
    const int lr = lane & 15, lc = lane >> 4;

    f32x4 acc[FM][FN];
#pragma unroll
    for (int i = 0; i < FM; ++i)
#pragma unroll
        for (int j = 0; j < FN; ++j) acc[i][j] = (f32x4){0.f, 0.f, 0.f, 0.f};

    for (int k0 = 0; k0 < K; k0 += 64) {
#pragma unroll
        for (int q = 0; q < NST / 4; ++q) {
            const int si = wv * (NST / 4) + q;
            const ushort* P; long ld; int row0; int st;
            if (si < OBH) {
                if (ALO && si >= NSA) { P = Al_g; st = si - NSA; }
                else                  { P = Ah_g; st = si; }
                ld = lda; row0 = m0;
            } else {
                const int sj = si - OBH;
                if (BLO && sj >= NSB) { P = Bl_g; st = sj - NSB; }
                else                  { P = Bh_g; st = sj; }
                ld = ldb; row0 = n0;
            }
            const int row = ((st >> 1) << 4) + lr;
            const int kc = ((st & 1) << 5) + (lc << 3);
            gll16(P + (size_t)(row0 + row) * ld + k0 + kc, &lds[si * 512]);
        }
        __syncthreads();
#pragma unroll
        for (int ks = 0; ks < 2; ++ks) {
            bf16x8 ah[FM], al[FM], bh[FN], bl[FN];
#pragma unroll
            for (int i = 0; i < FM; ++i) {
                const int st = (wm * FM + i) * 2 + ks;
                ah[i] = *(const bf16x8*)&lds[st * 512 + lane * 8];
                if (ALO) al[i] = *(const bf16x8*)&lds[(OAL + st) * 512 + lane * 8];
            }
#pragma unroll
            for (int j = 0; j < FN; ++j) {
                const int st = (wn * FN + j) * 2 + ks;
                bh[j] = *(const bf16x8*)&lds[(OBH + st) * 512 + lane * 8];
                if (BLO) bl[j] = *(const bf16x8*)&lds[(OBL + st) * 512 + lane * 8];
            }
#pragma unroll
            for (int i = 0; i < FM; ++i)
#pragma unroll
                for (int j = 0; j < FN; ++j) {
                    acc[i][j] = __builtin_amdgcn_mfma_f32_16x16x32_bf16(ah[i], bh[j], acc[i][j], 0, 0, 0);
                    if (BLO) acc[i][j] = __builtin_amdgcn_mfma_f32_16x16x32_bf16(ah[i], bl[j], acc[i][j], 0, 0, 0);
                    if (ALO) acc[i][j] = __builtin_amdgcn_mfma_f32_16x16x32_bf16(al[i], bh[j], acc[i][j], 0, 0, 0);
                }
        }
        __syncthreads();
    }

    const int fr = lane & 15, fc = lane >> 4;
#pragma unroll
    for (int i = 0; i < FM; ++i)
#pragma unroll
        for (int j = 0; j < FN; ++j) {
            const int mb = m0 + wm * FM * 16 + i * 16 + fc * 4;
            const int nb = n0 + wn * FN * 16 + j * 16 + fr;
            const float bv = bias ? bias[nb] : 0.f;
#pragma unroll
            for (int r = 0; r < 4; ++r) {
                const float v = acc[i][j][r] + bv;
                const size_t o = (size_t)(mb + r) * N + nb;
                if (Cf) Cf[o] = v;
                else if (Cbl) { const ushort hh = f2bf(v); Cbh[o] = hh; Cbl[o] = f2bf(v - bf2f(hh)); }
                else Cbh[o] = f2bf(v);
            }
        }
}

// ---------------- per-step kernels ----------------

__device__ __forceinline__ void gc_issue(
    const ushort* __restrict__ hc_h, const ushort* __restrict__ hc_l,
    const ushort* __restrict__ Whh_h, const ushort* __restrict__ Whh_l,
    int jc, int mb, int wv, int lr, int lc, int k0, ushort* dst)
{
#pragma unroll
    for (int q = 0; q < 5; ++q) {
        const int si = wv * 5 + q;
        const ushort* P; size_t rowoff; int ks;
        if (si < 4) {
            P = (si < 2) ? hc_h : hc_l;
            ks = si & 1;
            rowoff = (size_t)(mb * 16 + lr) * 1024;
        } else {
            const int sj = si - 4;
            P = (sj < 8) ? Whh_h : Whh_l;
            const int g = (sj & 7) >> 1;
            ks = sj & 1;
            rowoff = (size_t)(g * 1024 + jc * 16 + lr) * 1024;
        }
        gll16(P + rowoff + k0 + ks * 32 + lc * 8, dst + si * 512);
    }
}

// K1: gates + LSTM cell. grid (64 colgrp, 4 batchgrp); wave g = gate g.
// 3-buffer pipeline: raw s_barrier + counted vmcnt(5). (round-7 proven)
__global__ __launch_bounds__(256) void gates_cell(
    const ushort* __restrict__ hc_h, const ushort* __restrict__ hc_l,
    const ushort* __restrict__ Whh_h, const ushort* __restrict__ Whh_l,
    const float* __restrict__ xWt,
    float* __restrict__ c_buf, ushort* __restrict__ hy_h, ushort* __restrict__ hy_l)
{
    __shared__ ushort lds[3][10240];   // 60 KB
    __shared__ float gl[1024];         // 4 KB
    const int jc = blockIdx.x;
    const int mb = blockIdx.y;
    const int tid = threadIdx.x, lane = tid & 63, wv = tid >> 6;
    const int lr = lane & 15, lc = lane >> 4;

    f32x4 acc = (f32x4){0.f, 0.f, 0.f, 0.f};

    gc_issue(hc_h, hc_l, Whh_h, Whh_l, jc, mb, wv, lr, lc, 0, &lds[0][0]);
#pragma unroll
    for (int it = 0; it < 16; ++it) {
        if (it < 15) {
            gc_issue(hc_h, hc_l, Whh_h, Whh_l, jc, mb, wv, lr, lc,
                     (it + 1) * 64, &lds[(it + 1) % 3][0]);
            asm volatile("s_waitcnt vmcnt(5)" ::: "memory");
        } else {
            asm volatile("s_waitcnt vmcnt(0)" ::: "memory");
        }
        __builtin_amdgcn_s_barrier();
        __builtin_amdgcn_sched_barrier(0);
        const ushort* L = &lds[it % 3][0];
#pragma unroll
        for (int ks = 0; ks < 2; ++ks) {
            bf16x8 ah = *(const bf16x8*)&L[ks * 512 + lane * 8];
            bf16x8 al = *(const bf16x8*)&L[(2 + ks) * 512 + lane * 8];
            bf16x8 bh = *(const bf16x8*)&L[(4 + wv * 2 + ks) * 512 + lane * 8];
            bf16x8 bl = *(const bf16x8*)&L[(12 + wv * 2 + ks) * 512 + lane * 8];
            acc = __builtin_amdgcn_mfma_f32_16x16x32_bf16(ah, bh, acc, 0, 0, 0);
            acc = __builtin_amdgcn_mfma_f32_16x16x32_bf16(ah, bl, acc, 0, 0, 0);
            acc = __builtin_amdgcn_mfma_f32_16x16x32_bf16(al, bh, acc, 0, 0, 0);
        }
    }

    const int fr = lane & 15, fc = lane >> 4;
#pragma unroll
    for (int r = 0; r < 4; ++r)
        gl[wv * 256 + (fc * 4 + r) * 16 + fr] = acc[r];
    __syncthreads();

    const int bl_ = tid >> 4, cl = tid & 15;
    const int b = mb * 16 + bl_, col = jc * 16 + cl;
    const float* xw = xWt + (size_t)b * T_ * 4096;
    const float gi = gl[bl_ * 16 + cl]        + xw[col];
    const float gf = gl[256 + bl_ * 16 + cl]  + xw[1024 + col];
    const float gg = gl[512 + bl_ * 16 + cl]  + xw[2048 + col];
    const float go = gl[768 + bl_ * 16 + cl]  + xw[3072 + col];
    const int idx = b * 1024 + col;
    const float cn = sigmoidf_(gf) * c_buf[idx] + sigmoidf_(gi) * tanhf(gg);
    c_buf[idx] = cn;
    const float h = sigmoidf_(go) * tanhf(cn);
    const ushort hh = f2bf(h);
    hy_h[idx] = hh;
    hy_l[idx] = f2bf(h - bf2f(hh));
}

__device__ __forceinline__ void pair_issue(
    const ushort* __restrict__ Ah, const ushort* __restrict__ Al,
    const ushort* __restrict__ Bh, const ushort* __restrict__ Bl,
    size_t arow, size_t brow, int kb, int it, int lc, ushort* dst)
{
    const int k0 = kb + it * 64 + lc * 8;
    gll16(Ah + arow + k0,       dst);
    gll16(Ah + arow + k0 + 32,  dst + 512);
    gll16(Al + arow + k0,       dst + 1024);
    gll16(Al + arow + k0 + 32,  dst + 1536);
    gll16(Bh + brow + k0,       dst + 2048);
    gll16(Bh + brow + k0 + 32,  dst + 2560);
    gll16(Bl + brow + k0,       dst + 3072);
    gll16(Bl + brow + k0 + 32,  dst + 3584);
}

// K2: inp = hy @ W_in^T (C[b,c] = sum_k hy[b,k]*W_in[c,k]). grid (64 colgrp, 4 bgrp).
// Wave-private K-slice (256), dbuf counted vmcnt(8), LDS reduce. (round-7 outg scheme)
__global__ __launch_bounds__(256) void inp_k(
    const ushort* __restrict__ hy_h, const ushort* __restrict__ hy_l,
    const ushort* __restrict__ Win_h, const ushort* __restrict__ Win_l,
    ushort* __restrict__ inp_h, ushort* __restrict__ inp_l)
{
    __shared__ ushort st[4][2][4096];   // 64 KB
    __shared__ float red[1024];         // 4 KB
    const int nc = blockIdx.x, mb = blockIdx.y;
    const int tid = threadIdx.x, lane = tid & 63, wv = tid >> 6;
    const int lr = lane & 15, lc = lane >> 4;
    const int kb = wv * 256;
    const size_t arow = (size_t)(mb * 16 + lr) * 1024;
    const size_t brow = (size_t)(nc * 16 + lr) * 1024;
    ushort* stw = &st[wv][0][0];

    pair_issue(hy_h, hy_l, Win_h, Win_l, arow, brow, kb, 0, lc, stw);
    f32x4 acc = (f32x4){0.f, 0.f, 0.f, 0.f};
#pragma unroll
    for (int it = 0; it < 4; ++it) {
        if (it < 3) {
            pair_issue(hy_h, hy_l, Win_h, Win_l, arow, brow, kb, it + 1, lc,
                       stw + ((it + 1) & 1) * 4096);
            asm volatile("s_waitcnt vmcnt(8)" ::: "memory");
        } else {
            asm volatile("s_waitcnt vmcnt(0)" ::: "memory");
        }
        __builtin_amdgcn_sched_barrier(0);
        const ushort* W = stw + (it & 1) * 4096;
#pragma unroll
        for (int ks = 0; ks < 2; ++ks) {
            bf16x8 ah = *(const bf16x8*)&W[ks * 512 + lane * 8];
            bf16x8 al = *(const bf16x8*)&W[(2 + ks) * 512 + lane * 8];
            bf16x8 bh = *(const bf16x8*)&W[(4 + ks) * 512 + lane * 8];
            bf16x8 bl = *(const bf16x8*)&W[(6 + ks) * 512 + lane * 8];
            acc = __builtin_amdgcn_mfma_f32_16x16x32_bf16(ah, bh, acc, 0, 0, 0);
            acc = __builtin_amdgcn_mfma_f32_16x16x32_bf16(ah, bl, acc, 0, 0, 0);
            acc = __builtin_amdgcn_mfma_f32_16x16x32_bf16(al, bh, acc, 0, 0, 0);
        }
    }

    const int fc = lane >> 4, fr = lane & 15;
#pragma unroll
    for (int r = 0; r < 4; ++r)
        red[wv * 256 + (fc * 4 + r) * 16 + fr] = acc[r];
    __syncthreads();

    const int bl_ = tid >> 4, tl = tid & 15;
    const float v = red[bl_ * 16 + tl] + red[256 + bl_ * 16 + tl]
                  + red[512 + bl_ * 16 + tl] + red[768 + bl_ * 16 + tl];
    const int b = mb * 16 + bl_, col = nc * 16 + tl;
    const int idx = b * 1024 + col;
    const ushort hh = f2bf(v);
    inp_h[idx] = hh;
    inp_l[idx] = f2bf(v - bf2f(hh));
}

// K3: attention. One block per batch (512 thr); streams dc (bf16) once;
// scores -> softmax -> wctx planes. (round-4 proven)
__global__ __launch_bounds__(512) void attn_k(
    const ushort* __restrict__ dc_all,
    const ushort* __restrict__ inp_h, const ushort* __restrict__ inp_l,
    ushort* __restrict__ wc_h, ushort* __restrict__ wc_l,
    const float* __restrict__ mask)
{
    const int b = blockIdx.x;
    const int tid = threadIdx.x;
    const int lane = tid & 63;
    const int wid = tid >> 6;

    __shared__ alignas(16) float sinp[IN_];
    __shared__ float sc[S_];

    sinp[tid]       = bf2f(inp_h[b * 1024 + tid])       + bf2f(inp_l[b * 1024 + tid]);
    sinp[tid + 512] = bf2f(inp_h[b * 1024 + 512 + tid]) + bf2f(inp_l[b * 1024 + 512 + tid]);
    __syncthreads();

    const ushort* dc = dc_all + (size_t)b * S_ * IN_;
    for (int s = wid; s < S_; s += 8) {
        const ushort* row = dc + (size_t)s * IN_;
        float sum = 0.f;
#pragma unroll
        for (int it = 0; it < 2; ++it) {
            const int e = it * 512 + lane * 8;
            const uint4 v = *(const uint4*)(row + e);
            const float4 w0 = *(const float4*)&sinp[e];
            const float4 w1 = *(const float4*)&sinp[e + 4];
            sum += bf2f(v.x & 0xffff) * w0.x + bf2f(v.x >> 16) * w0.y
                 + bf2f(v.y & 0xffff) * w0.z + bf2f(v.y >> 16) * w0.w
                 + bf2f(v.z & 0xffff) * w1.x + bf2f(v.z >> 16) * w1.y
                 + bf2f(v.w & 0xffff) * w1.z + bf2f(v.w >> 16) * w1.w;
        }
#pragma unroll
        for (int off = 32; off > 0; off >>= 1) sum += __shfl_xor(sum, off);
        if (lane == 0)
            sc[s] = sum - (1.0f - mask[(size_t)b * S_ + s]) * 100000.0f;
    }
    __syncthreads();

    if (tid < 64) {
        float v0 = sc[tid], v1 = sc[tid + 64];
        float mx = fmaxf(v0, v1);
#pragma unroll
        for (int off = 32; off > 0; off >>= 1) mx = fmaxf(mx, __shfl_xor(mx, off));
        float e0 = expf(v0 - mx), e1 = expf(v1 - mx);
        float ssum = e0 + e1;
#pragma unroll
        for (int off = 32; off > 0; off >>= 1) ssum += __shfl_xor(ssum, off);
        const float inv = 1.0f / ssum;
        sc[tid] = e0 * inv;
        sc[tid + 64] = e1 * inv;
    }
    __syncthreads();

    float ax = 0.f, ay = 0.f;
#pragma unroll 4
    for (int s = 0; s < S_; ++s) {
        const float a = sc[s];
        const unsigned v = *(const unsigned*)(dc + (size_t)s * IN_ + 2 * tid);
        ax += a * bf2f(v & 0xffff);
        ay += a * bf2f(v >> 16);
    }
    const ushort hx = f2bf(ax), hy2 = f2bf(ay);
    wc_h[(size_t)b * 1024 + 2 * tid]     = hx;
    wc_h[(size_t)b * 1024 + 2 * tid + 1] = hy2;
    wc_l[(size_t)b * 1024 + 2 * tid]     = f2bf(ax - bf2f(hx));
    wc_l[(size_t)b * 1024 + 2 * tid + 1] = f2bf(ay - bf2f(hy2));
}

// K4: h = tanh(wctx @ Wo1^T + hy @ Woi^T). grid (64 colgrp, 4 batchgrp).
// Wave-private K slices over both halves, dbuf counted vmcnt(8). (round-6 proven)
__global__ __launch_bounds__(256) void out_h(
    const ushort* __restrict__ wc_h, const ushort* __restrict__ wc_l,
    const ushort* __restrict__ hy_h, const ushort* __restrict__ hy_l,
    const ushort* __restrict__ Wo1_h, const ushort* __restrict__ Wo1_l,
    const ushort* __restrict__ Woi_h, const ushort* __restrict__ Woi_l,
    float* __restrict__ outp, ushort* __restrict__ hc_h, ushort* __restrict__ hc_l)
{
    __shared__ ushort st[4][2][4096];   // 64 KB
    __shared__ float red[1024];         // 4 KB
    const int nc = blockIdx.x;
    const int mb = blockIdx.y;
    const int tid = threadIdx.x, lane = tid & 63, wv = tid >> 6;
    const int lr = lane & 15, lc = lane >> 4;
    const int kb = wv * 256;
    const size_t arow = (size_t)(mb * 16 + lr) * 1024;
    const size_t brow = (size_t)(nc * 16 + lr) * 1024;
    ushort* stw = &st[wv][0][0];

#define OH_ISSUE(IT, BUF)                                                      \
    {                                                                          \
        const ushort* Ah_ = ((IT) < 4) ? wc_h : hy_h;                          \
        const ushort* Al_ = ((IT) < 4) ? wc_l : hy_l;                          \
        const ushort* Bh_ = ((IT) < 4) ? Wo1_h : Woi_h;                        \
        const ushort* Bl_ = ((IT) < 4) ? Wo1_l : Woi_l;                        \
        pair_issue(Ah_, Al_, Bh_, Bl_, arow, brow, kb, (IT) & 3, lc,           \
                   stw + (BUF) * 4096);                                        \
    }

    f32x4 acc = (f32x4){0.f, 0.f, 0.f, 0.f};
    OH_ISSUE(0, 0)
#pragma unroll
    for (int it = 0; it < 8; ++it) {
        if (it < 7) {
            OH_ISSUE(it + 1, (it + 1) & 1)
            asm volatile("s_waitcnt vmcnt(8)" ::: "memory");
        } else {
            asm volatile("s_waitcnt vmcnt(0)" ::: "memory");
        }
        __builtin_amdgcn_sched_barrier(0);
        const ushort* W = stw + (it & 1) * 4096;
#pragma unroll
        for (int ks = 0; ks < 2; ++ks) {
            bf16x8 ah = *(const bf16x8*)&W[ks * 512 + lane * 8];
            bf16x8 al = *(const bf16x8*)&W[(2 + ks) * 512 + lane * 8];
            bf16x8 bh = *(const bf16x8*)&W[(4 + ks) * 512 + lane * 8];
            bf16x8 bl = *(const bf16x8*)&W[(6 + ks) * 512 + lane * 8];
            acc = __builtin_amdgcn_mfma_f32_16x16x32_bf16(ah, bh, acc, 0, 0, 0);
            acc = __builtin_amdgcn_mfma_f32_16x16x32_bf16(ah, bl, acc, 0, 0, 0);
            acc = __builtin_amdgcn_mfma_f32_16x16x32_bf16(al, bh, acc, 0, 0, 0);
        }
    }
#undef OH_ISSUE

    const int fc = lane >> 4, fr = lane & 15;
#pragma unroll
    for (int r = 0; r < 4; ++r)
        red[wv * 256 + (fc * 4 + r) * 16 + fr] = acc[r];
    __syncthreads();

    const int bl_ = tid >> 4, cl = tid & 15;
    float v = red[bl_ * 16 + cl] + red[256 + bl_ * 16 + cl]
            + red[512 + bl_ * 16 + cl] + red[768 + bl_ * 16 + cl];
    v = tanhf(v);
    const int b = mb * 16 + bl_, col = nc * 16 + cl;
    outp[(size_t)b * T_ * 1024 + col] = v;
    const int idx = b * 1024 + col;
    const ushort hh = f2bf(v);
    hc_h[idx] = hh;
    hc_l[idx] = f2bf(v - bf2f(hh));
}

// ---------------- conversion / misc ----------------
__global__ __launch_bounds__(256) void cvt2_k(
    const float* __restrict__ in, ushort* __restrict__ hi, ushort* __restrict__ lo, int n4)
{
    const int i = blockIdx.x * 256 + threadIdx.x;
    if (i >= n4) return;
    const float4 v = ((const float4*)in)[i];
    ushort4 h, l;
    h.x = f2bf(v.x); l.x = f2bf(v.x - bf2f(h.x));
    h.y = f2bf(v.y); l.y = f2bf(v.y - bf2f(h.y));
    h.z = f2bf(v.z); l.z = f2bf(v.z - bf2f(h.z));
    h.w = f2bf(v.w); l.w = f2bf(v.w - bf2f(h.w));
    ((ushort4*)hi)[i] = h;
    ((ushort4*)lo)[i] = l;
}

__global__ __launch_bounds__(256) void cvt1_k(
    const float* __restrict__ in, ushort* __restrict__ hi, int n4)
{
    const int i = blockIdx.x * 256 + threadIdx.x;
    if (i >= n4) return;
    const float4 v = ((const float4*)in)[i];
    ushort4 h;
    h.x = f2bf(v.x); h.y = f2bf(v.y); h.z = f2bf(v.z); h.w = f2bf(v.w);
    ((ushort4*)hi)[i] = h;
}

__global__ __launch_bounds__(256) void cvt2s_k(
    const float* __restrict__ in, long instride4, int rowlen4,
    ushort* __restrict__ hi, ushort* __restrict__ lo, int n4)
{
    const int i = blockIdx.x * 256 + threadIdx.x;
    if (i >= n4) return;
    const int r = i / rowlen4, c = i - r * rowlen4;
    const float4 v = ((const float4*)in)[(size_t)r * instride4 + c];
    ushort4 h, l;
    h.x = f2bf(v.x); l.x = f2bf(v.x - bf2f(h.x));
    h.y = f2bf(v.y); l.y = f2bf(v.y - bf2f(h.y));
    h.z = f2bf(v.z); l.z = f2bf(v.z - bf2f(h.z));
    h.w = f2bf(v.w); l.w = f2bf(v.w - bf2f(h.w));
    ((ushort4*)hi)[i] = h;
    ((ushort4*)lo)[i] = l;
}

__global__ void transpose_k(const float* __restrict__ in, float* __restrict__ out)
{
    __shared__ float tile[32][33];
    const int bx = blockIdx.x * 32, by = blockIdx.y * 32;
    const int tx = threadIdx.x, ty = threadIdx.y;   // (32,8)
#pragma unroll
    for (int i = 0; i < 32; i += 8)
        tile[ty + i][tx] = in[(size_t)(by + ty + i) * 1024 + bx + tx];
    __syncthreads();
#pragma unroll
    for (int i = 0; i < 32; i += 8)
        out[(size_t)(bx + ty + i) * 1024 + by + tx] = tile[tx][ty + i];
}

__global__ __launch_bounds__(256) void add_bias_k(
    const float* __restrict__ a, const float* __restrict__ b, float* __restrict__ o, int n)
{
    const int i = blockIdx.x * 256 + threadIdx.x;
    if (i < n) o[i] = a[i] + b[i];
}

__global__ __launch_bounds__(256) void finalize_k(
    const float* __restrict__ out_full, const float* __restrict__ c_buf,
    float* __restrict__ hT, float* __restrict__ cT)
{
    const int idx = blockIdx.x * 256 + threadIdx.x;
    const int b = idx >> 10, j = idx & 1023;
    hT[idx] = out_full[(size_t)b * T_ * H_ + (size_t)(T_ - 1) * H_ + j];
    cT[idx] = c_buf[idx];
}

extern "C" void kernel_launch(void* const* d_in, const int* in_sizes, int n_in,
                              void* d_out, int out_size, void* d_ws, size_t ws_size,
                              hipStream_t stream) {
    const float* target = (const float*)d_in[0];
    const float* h0     = (const float*)d_in[1];
    const float* c0     = (const float*)d_in[2];
    const float* ctx    = (const float*)d_in[3];
    const float* mask   = (const float*)d_in[4];
    const float* W_ih   = (const float*)d_in[5];
    const float* b_ih   = (const float*)d_in[6];
    const float* W_hh   = (const float*)d_in[7];
    const float* b_hh   = (const float*)d_in[8];
    const float* W_in   = (const float*)d_in[9];
    const float* W_ctx  = (const float*)d_in[10];
    const float* W_out  = (const float*)d_in[11];

    float* out = (float*)d_out;
    float* hT  = out + (size_t)B_ * T_ * H_;
    float* cT  = hT + (size_t)B_ * H_;

    // ---- workspace layout ----
    char* p = (char*)d_ws;
    float*  xW    = (float*)p;             p += 8388608ull * 4;    // 33.55 MB
    ushort* dc_b  = (ushort*)p;            p += 8388608ull * 2;    // 16.78 MB
    ushort* Whh_h = (ushort*)p;            p += 4194304ull * 2;
    ushort* Whh_l = (ushort*)p;            p += 4194304ull * 2;
    ushort* Win_h = (ushort*)p;            p += 1048576ull * 2;
    ushort* Win_l = (ushort*)p;            p += 1048576ull * 2;
    ushort* Wo1_h = (ushort*)p;            p += 1048576ull * 2;
    ushort* Wo1_l = (ushort*)p;            p += 1048576ull * 2;
    ushort* Woi_h = (ushort*)p;            p += 1048576ull * 2;
    ushort* Woi_l = (ushort*)p;            p += 1048576ull * 2;
    float*  bias_sum = (float*)p;          p += 4096ull * 4;
    float*  c_buf = (float*)p;             p += 65536ull * 4;
    ushort* hy_h  = (ushort*)p;            p += 65536ull * 2;
    ushort* hy_l  = (ushort*)p;            p += 65536ull * 2;
    ushort* hc_h  = (ushort*)p;            p += 65536ull * 2;
    ushort* hc_l  = (ushort*)p;            p += 65536ull * 2;
    ushort* wc_h  = (ushort*)p;            p += 65536ull * 2;
    ushort* wc_l  = (ushort*)p;            p += 65536ull * 2;
    ushort* inp_h = (ushort*)p;            p += 65536ull * 2;
    ushort* inp_l = (ushort*)p;            p += 65536ull * 2;
    ushort* trans = (ushort*)p;                                    // ~42 MB transient

    // transient phase A: ctx bf16 + W_ctx planes
    ushort* ctx_h  = trans;                            // 16,777,216 elems (33.55 MB)
    ushort* Wctx_h = trans + 16777216;                 // 2,097,152
    ushort* Wctx_l = trans + 18874368;                 // 2,097,152
    // transient phase B: WinT_f + WinT planes + Wo2 planes
    float*  WinT_f = (float*)trans;                    // 1,048,576 f32
    ushort* WinT_h = trans + 2097152;                  // 1,048,576
    ushort* WinT_l = trans + 3145728;
    ushort* Wo2_h  = trans + 4194304;
    ushort* Wo2_l  = trans + 5242880;
    // transient phase C: target planes + W_ih planes
    ushort* tgt_h  = trans;
    ushort* tgt_l  = trans + 2097152;
    ushort* Wih_h  = trans + 4194304;
    ushort* Wih_l  = trans + 8388608;

    // ---- preamble ----
    add_bias_k<<<16, 256, 0, stream>>>(b_ih, b_hh, bias_sum, 4 * H_);
    cvt2_k<<<4096, 256, 0, stream>>>(W_hh, Whh_h, Whh_l, 1048576);
    cvt2_k<<<1024, 256, 0, stream>>>(W_in, Win_h, Win_l, 262144);
    cvt2s_k<<<1024, 256, 0, stream>>>(W_out, 512, 256, Wo1_h, Wo1_l, 262144);

    // dense_ctx (bf16) = ctx @ W_ctx^T
    cvt1_k<<<16384, 256, 0, stream>>>(ctx, ctx_h, 4194304);
    cvt2_k<<<2048, 256, 0, stream>>>(W_ctx, Wctx_h, Wctx_l, 524288);
    gemm_bf<4, 4, false, true><<<dim3(8, 64), 256, 0, stream>>>(
        ctx_h, nullptr, 2048, Wctx_h, Wctx_l, 2048,
        2048, 1024, nullptr, dc_b, nullptr, nullptr);

    // Woi = Wo2 @ W_in (via WinT so B^T = W_in)
    transpose_k<<<dim3(32, 32), dim3(32, 8), 0, stream>>>(W_in, WinT_f);
    cvt2_k<<<1024, 256, 0, stream>>>(WinT_f, WinT_h, WinT_l, 262144);
    cvt2s_k<<<1024, 256, 0, stream>>>(W_out + 1024, 512, 256, Wo2_h, Wo2_l, 262144);
    gemm_bf<4, 4, true, true><<<dim3(8, 8), 256, 0, stream>>>(
        Wo2_h, Wo2_l, 1024, WinT_h, WinT_l, 1024,
        1024, 1024, nullptr, Woi_h, Woi_l, nullptr);

    // xW = target @ W_ih^T + bias
    cvt2_k<<<2048, 256, 0, stream>>>(target, tgt_h, tgt_l, 524288);
    cvt2_k<<<4096, 256, 0, stream>>>(W_ih, Wih_h, Wih_l, 1048576);
    gemm_bf<4, 4, true, true><<<dim3(32, 16), 256, 0, stream>>>(
        tgt_h, tgt_l, 1024, Wih_h, Wih_l, 1024,
        1024, 4096, xW, nullptr, nullptr, bias_sum);

    // loop state
    cvt2_k<<<64, 256, 0, stream>>>(h0, hc_h, hc_l, 16384);
    hipMemcpyAsync(c_buf, c0, sizeof(float) * B_ * H_, hipMemcpyDeviceToDevice, stream);

    for (int t = 0; t < T_; ++t) {
        gates_cell<<<dim3(64, 4), 256, 0, stream>>>(
            hc_h, hc_l, Whh_h, Whh_l, xW + (size_t)t * 4096, c_buf, hy_h, hy_l);
        inp_k<<<dim3(64, 4), 256, 0, stream>>>(
            hy_h, hy_l, Win_h, Win_l, inp_h, inp_l);
        attn_k<<<64, 512, 0, stream>>>(dc_b, inp_h, inp_l, wc_h, wc_l, mask);
        out_h<<<dim3(64, 4), 256, 0, stream>>>(
            wc_h, wc_l, hy_h, hy_l, Wo1_h, Wo1_l, Woi_h, Woi_l,
            out + (size_t)t * H_, hc_h, hc_l);
    }

    finalize_k<<<256, 256, 0, stream>>>(out, c_buf, hT, cT);
}

// Round 11
// 1338.512 us; speedup vs baseline: 2.5381x; 1.3231x over previous
//
#include <hip/hip_runtime.h>
#include <cstddef>

#define B_ 64
#define T_ 32
#define S_ 128
#define IN_ 1024
#define H_ 1024

typedef __bf16 bf16x8 __attribute__((ext_vector_type(8)));
typedef float f32x4 __attribute__((ext_vector_type(4)));

__device__ __forceinline__ float sigmoidf_(float x) { return 1.0f / (1.0f + expf(-x)); }

__device__ __forceinline__ ushort f2bf(float x) {
    unsigned u = __builtin_bit_cast(unsigned, x);
    unsigned r = (u + 0x7fffu + ((u >> 16) & 1u)) >> 16;
    return (ushort)r;
}
__device__ __forceinline__ float bf2f(ushort h) {
    unsigned u = ((unsigned)h) << 16;
    return __builtin_bit_cast(float, u);
}

// async global->LDS, 16B per lane; lds dest wave-uniform (HW adds lane*16).
__device__ __forceinline__ void gll16(const ushort* g, ushort* l) {
    __builtin_amdgcn_global_load_lds(
        (const __attribute__((address_space(1))) void*)g,
        (__attribute__((address_space(3))) void*)l,
        16, 0, 0);
}

// ---------------- big-GEMM (preamble): C = A @ B^T, split-bf16 planes ----------
// Optional blockIdx.z batching via element strides Az/Bz/Cz.
// out modes: Cf!=null -> fp32 (+bias); else Cbl!=null -> hi/lo planes; else Cbh bf16.
template<int FM, int FN, bool ALO, bool BLO>
__global__ __launch_bounds__(256) void gemm_bf(
    const ushort* __restrict__ Ah_g, const ushort* __restrict__ Al_g, long lda,
    const ushort* __restrict__ Bh_g, const ushort* __restrict__ Bl_g, long ldb,
    int K, int N,
    float* __restrict__ Cf, ushort* __restrict__ Cbh, ushort* __restrict__ Cbl,
    const float* __restrict__ bias,
    long Az, long Bz, long Cz)
{
    constexpr int NSA = 4 * FM;
    constexpr int NSB = 4 * FN;
    constexpr int OAL = NSA;
    constexpr int OBH = NSA * (ALO ? 2 : 1);
    constexpr int OBL = OBH + NSB;
    constexpr int NST = OBH + NSB * (BLO ? 2 : 1);
    __shared__ ushort lds[NST * 512];

    const long z = blockIdx.z;
    Ah_g += z * Az; if (ALO) Al_g += z * Az;
    Bh_g += z * Bz; if (BLO) Bl_g += z * Bz;
    if (Cf) Cf += z * Cz;
    if (Cbh) Cbh += z * Cz;
    if (Cbl) Cbl += z * Cz;

    const int tid = threadIdx.x;
    const int lane = tid & 63, wv = tid >> 6;
    const int wm = wv >> 1, wn = wv & 1;
    const int m0 = blockIdx.y * (FM * 32), n0 = blockIdx.x * (FN * 32);
    const int lr = lane & 15, lc = lane >> 4;

    f32x4 acc[FM][FN];
#pragma unroll
    for (int i = 0; i < FM; ++i)
#pragma unroll
        for (int j = 0; j < FN; ++j) acc[i][j] = (f32x4){0.f, 0.f, 0.f, 0.f};

    for (int k0 = 0; k0 < K; k0 += 64) {
#pragma unroll
        for (int q = 0; q < NST / 4; ++q) {
            const int si = wv * (NST / 4) + q;
            const ushort* P; long ld; int row0; int st;
            if (si < OBH) {
                if (ALO && si >= NSA) { P = Al_g; st = si - NSA; }
                else                  { P = Ah_g; st = si; }
                ld = lda; row0 = m0;
            } else {
                const int sj = si - OBH;
                if (BLO && sj >= NSB) { P = Bl_g; st = sj - NSB; }
                else                  { P = Bh_g; st = sj; }
                ld = ldb; row0 = n0;
            }
            const int row = ((st >> 1) << 4) + lr;
            const int kc = ((st & 1) << 5) + (lc << 3);
            gll16(P + (size_t)(row0 + row) * ld + k0 + kc, &lds[si * 512]);
        }
        __syncthreads();
#pragma unroll
        for (int ks = 0; ks < 2; ++ks) {
            bf16x8 ah[FM], al[FM], bh[FN], bl[FN];
#pragma unroll
            for (int i = 0; i < FM; ++i) {
                const int st = (wm * FM + i) * 2 + ks;
                ah[i] = *(const bf16x8*)&lds[st * 512 + lane * 8];
                if (ALO) al[i] = *(const bf16x8*)&lds[(OAL + st) * 512 + lane * 8];
            }
#pragma unroll
            for (int j = 0; j < FN; ++j) {
                const int st = (wn * FN + j) * 2 + ks;
                bh[j] = *(const bf16x8*)&lds[(OBH + st) * 512 + lane * 8];
                if (BLO) bl[j] = *(const bf16x8*)&lds[(OBL + st) * 512 + lane * 8];
            }
#pragma unroll
            for (int i = 0; i < FM; ++i)
#pragma unroll
                for (int j = 0; j < FN; ++j) {
                    acc[i][j] = __builtin_amdgcn_mfma_f32_16x16x32_bf16(ah[i], bh[j], acc[i][j], 0, 0, 0);
                    if (BLO) acc[i][j] = __builtin_amdgcn_mfma_f32_16x16x32_bf16(ah[i], bl[j], acc[i][j], 0, 0, 0);
                    if (ALO) acc[i][j] = __builtin_amdgcn_mfma_f32_16x16x32_bf16(al[i], bh[j], acc[i][j], 0, 0, 0);
                }
        }
        __syncthreads();
    }

    const int fr = lane & 15, fc = lane >> 4;
#pragma unroll
    for (int i = 0; i < FM; ++i)
#pragma unroll
        for (int j = 0; j < FN; ++j) {
            const int mb = m0 + wm * FM * 16 + i * 16 + fc * 4;
            const int nb = n0 + wn * FN * 16 + j * 16 + fr;
            const float bv = bias ? bias[nb] : 0.f;
#pragma unroll
            for (int r = 0; r < 4; ++r) {
                const float v = acc[i][j][r] + bv;
                const size_t o = (size_t)(mb + r) * N + nb;
                if (Cf) Cf[o] = v;
                else if (Cbl) { const ushort hh = f2bf(v); Cbh[o] = hh; Cbl[o] = f2bf(v - bf2f(hh)); }
                else Cbh[o] = f2bf(v);
            }
        }
}

// ---------------- per-step kernels ----------------

__device__ __forceinline__ void gc_issue(
    const ushort* __restrict__ hc_h, const ushort* __restrict__ hc_l,
    const ushort* __restrict__ Whh_h, const ushort* __restrict__ Whh_l,
    int jc, int mb, int wv, int lr, int lc, int k0, ushort* dst)
{
#pragma unroll
    for (int q = 0; q < 5; ++q) {
        const int si = wv * 5 + q;
        const ushort* P; size_t rowoff; int ks;
        if (si < 4) {
            P = (si < 2) ? hc_h : hc_l;
            ks = si & 1;
            rowoff = (size_t)(mb * 16 + lr) * 1024;
        } else {
            const int sj = si - 4;
            P = (sj < 8) ? Whh_h : Whh_l;
            const int g = (sj & 7) >> 1;
            ks = sj & 1;
            rowoff = (size_t)(g * 1024 + jc * 16 + lr) * 1024;
        }
        gll16(P + rowoff + k0 + ks * 32 + lc * 8, dst + si * 512);
    }
}

// K1: gates + LSTM cell. grid (64 colgrp, 4 batchgrp); wave g = gate g.
// 3-buffer pipeline: raw s_barrier + counted vmcnt(5). (round-7 proven)
__global__ __launch_bounds__(256) void gates_cell(
    const ushort* __restrict__ hc_h, const ushort* __restrict__ hc_l,
    const ushort* __restrict__ Whh_h, const ushort* __restrict__ Whh_l,
    const float* __restrict__ xWt,
    float* __restrict__ c_buf, ushort* __restrict__ hy_h, ushort* __restrict__ hy_l)
{
    __shared__ ushort lds[3][10240];   // 60 KB
    __shared__ float gl[1024];         // 4 KB
    const int jc = blockIdx.x;
    const int mb = blockIdx.y;
    const int tid = threadIdx.x, lane = tid & 63, wv = tid >> 6;
    const int lr = lane & 15, lc = lane >> 4;

    f32x4 acc = (f32x4){0.f, 0.f, 0.f, 0.f};

    gc_issue(hc_h, hc_l, Whh_h, Whh_l, jc, mb, wv, lr, lc, 0, &lds[0][0]);
#pragma unroll
    for (int it = 0; it < 16; ++it) {
        if (it < 15) {
            gc_issue(hc_h, hc_l, Whh_h, Whh_l, jc, mb, wv, lr, lc,
                     (it + 1) * 64, &lds[(it + 1) % 3][0]);
            asm volatile("s_waitcnt vmcnt(5)" ::: "memory");
        } else {
            asm volatile("s_waitcnt vmcnt(0)" ::: "memory");
        }
        __builtin_amdgcn_s_barrier();
        __builtin_amdgcn_sched_barrier(0);
        const ushort* L = &lds[it % 3][0];
#pragma unroll
        for (int ks = 0; ks < 2; ++ks) {
            bf16x8 ah = *(const bf16x8*)&L[ks * 512 + lane * 8];
            bf16x8 al = *(const bf16x8*)&L[(2 + ks) * 512 + lane * 8];
            bf16x8 bh = *(const bf16x8*)&L[(4 + wv * 2 + ks) * 512 + lane * 8];
            bf16x8 bl = *(const bf16x8*)&L[(12 + wv * 2 + ks) * 512 + lane * 8];
            acc = __builtin_amdgcn_mfma_f32_16x16x32_bf16(ah, bh, acc, 0, 0, 0);
            acc = __builtin_amdgcn_mfma_f32_16x16x32_bf16(ah, bl, acc, 0, 0, 0);
            acc = __builtin_amdgcn_mfma_f32_16x16x32_bf16(al, bh, acc, 0, 0, 0);
        }
    }

    const int fr = lane & 15, fc = lane >> 4;
#pragma unroll
    for (int r = 0; r < 4; ++r)
        gl[wv * 256 + (fc * 4 + r) * 16 + fr] = acc[r];
    __syncthreads();

    const int bl_ = tid >> 4, cl = tid & 15;
    const int b = mb * 16 + bl_, col = jc * 16 + cl;
    const float* xw = xWt + (size_t)b * T_ * 4096;
    const float gi = gl[bl_ * 16 + cl]        + xw[col];
    const float gf = gl[256 + bl_ * 16 + cl]  + xw[1024 + col];
    const float gg = gl[512 + bl_ * 16 + cl]  + xw[2048 + col];
    const float go = gl[768 + bl_ * 16 + cl]  + xw[3072 + col];
    const int idx = b * 1024 + col;
    const float cn = sigmoidf_(gf) * c_buf[idx] + sigmoidf_(gi) * tanhf(gg);
    c_buf[idx] = cn;
    const float h = sigmoidf_(go) * tanhf(cn);
    const ushort hh = f2bf(h);
    hy_h[idx] = hh;
    hy_l[idx] = f2bf(h - bf2f(hh));
}

// K2: raw scores from fp32 E. grid (64 b, 4 sgroup of 32).
// sc_raw[b,s] = E[b,s,:]·hy[b,:] - neg. (round-7 proven)
__global__ __launch_bounds__(256) void scores_k(
    const float* __restrict__ E,
    const ushort* __restrict__ hy_h, const ushort* __restrict__ hy_l,
    const float* __restrict__ mask, float* __restrict__ sc_raw)
{
    const int b = blockIdx.x, sg = blockIdx.y;
    const int tid = threadIdx.x, lane = tid & 63, wv = tid >> 6;
    __shared__ alignas(16) float sinp[IN_];
#pragma unroll
    for (int i = 0; i < 4; ++i) {
        const int j = tid + i * 256;
        sinp[j] = bf2f(hy_h[b * 1024 + j]) + bf2f(hy_l[b * 1024 + j]);
    }
    __syncthreads();
    const float4* s4 = (const float4*)sinp;
#pragma unroll
    for (int r = 0; r < 8; ++r) {
        const int s = sg * 32 + wv * 8 + r;
        const float4* row = (const float4*)(E + ((size_t)b * S_ + s) * 1024);
        float sum = 0.f;
#pragma unroll
        for (int i = 0; i < 4; ++i) {
            const float4 v = row[lane + i * 64];
            const float4 w = s4[lane + i * 64];
            sum += v.x * w.x + v.y * w.y + v.z * w.z + v.w * w.w;
        }
#pragma unroll
        for (int off = 32; off > 0; off >>= 1) sum += __shfl_xor(sum, off);
        if (lane == 0)
            sc_raw[b * S_ + s] = sum - (1.0f - mask[(size_t)b * S_ + s]) * 100000.0f;
    }
}

__device__ __forceinline__ void og_issue(
    const ushort* __restrict__ hy_h, const ushort* __restrict__ hy_l,
    const ushort* __restrict__ Woi_h, const ushort* __restrict__ Woi_l,
    size_t arow, size_t brow, int kb, int it, int lc, ushort* dst)
{
    const int k0 = kb + it * 64 + lc * 8;
    gll16(hy_h + arow + k0,       dst);
    gll16(hy_h + arow + k0 + 32,  dst + 512);
    gll16(hy_l + arow + k0,       dst + 1024);
    gll16(hy_l + arow + k0 + 32,  dst + 1536);
    gll16(Woi_h + brow + k0,      dst + 2048);
    gll16(Woi_h + brow + k0 + 32, dst + 2560);
    gll16(Woi_l + brow + k0,      dst + 3072);
    gll16(Woi_l + brow + k0 + 32, dst + 3584);
}

// K3: out = tanh( softmax(sc) @ Gt + hy @ Woi^T ). grid (64 colgrp, 4 batchgrp).
// Softmax per 16-lane group (redundant, deterministic). G-part: bf16 Gt stream.
// MFMA part: wave-private K-split dbuf, counted vmcnt. (round-10 logic, passed values)
__global__ __launch_bounds__(256) void outg_k(
    const float* __restrict__ sc_raw,
    const ushort* __restrict__ Gt_b,
    const ushort* __restrict__ hy_h, const ushort* __restrict__ hy_l,
    const ushort* __restrict__ Woi_h, const ushort* __restrict__ Woi_l,
    float* __restrict__ outp, ushort* __restrict__ hc_h, ushort* __restrict__ hc_l)
{
    __shared__ ushort st[4][2][4096];   // 64 KB
    __shared__ float aS[16][128];       // 8 KB
    __shared__ float red[1024];         // 4 KB
    const int nc = blockIdx.x, mb = blockIdx.y;
    const int tid = threadIdx.x, lane = tid & 63, wv = tid >> 6;
    const int lr = lane & 15, lc = lane >> 4;
    const int kb = wv * 256;
    const size_t arow = (size_t)(mb * 16 + lr) * 1024;
    const size_t brow = (size_t)(nc * 16 + lr) * 1024;
    ushort* stw = &st[wv][0][0];

    og_issue(hy_h, hy_l, Woi_h, Woi_l, arow, brow, kb, 0, lc, stw);

    // softmax for this block's 16 batches (16 lanes per batch, in-wave)
    const int bl_ = tid >> 4, tl = tid & 15;
    const int b = mb * 16 + bl_;
    float v[8], mx = -3.4e38f;
#pragma unroll
    for (int i = 0; i < 8; ++i) {
        v[i] = sc_raw[b * S_ + tl * 8 + i];
        mx = fmaxf(mx, v[i]);
    }
#pragma unroll
    for (int off = 1; off < 16; off <<= 1) mx = fmaxf(mx, __shfl_xor(mx, off));
    float sm = 0.f;
#pragma unroll
    for (int i = 0; i < 8; ++i) { v[i] = expf(v[i] - mx); sm += v[i]; }
#pragma unroll
    for (int off = 1; off < 16; off <<= 1) sm += __shfl_xor(sm, off);
    const float inv = 1.0f / sm;
#pragma unroll
    for (int i = 0; i < 8; ++i) aS[bl_][tl * 8 + i] = v[i] * inv;
    asm volatile("s_waitcnt lgkmcnt(0)" ::: "memory");

    // G part: a @ Gt[b][col][:]  (Gt bf16 single plane)
    const int c = nc * 16 + tl;
    const ushort* gt = Gt_b + ((size_t)b * 1024 + c) * 128;
    float accg = 0.f;
#pragma unroll
    for (int i = 0; i < 16; ++i) {
        const uint4 g4 = *(const uint4*)(gt + i * 8);
        const float* a = &aS[bl_][i * 8];
        accg += a[0] * bf2f(g4.x & 0xffff) + a[1] * bf2f(g4.x >> 16)
              + a[2] * bf2f(g4.y & 0xffff) + a[3] * bf2f(g4.y >> 16)
              + a[4] * bf2f(g4.z & 0xffff) + a[5] * bf2f(g4.z >> 16)
              + a[6] * bf2f(g4.w & 0xffff) + a[7] * bf2f(g4.w >> 16);
    }

    // MFMA part: hy @ Woi^T, wave-private K slice, dbuf counted vmcnt
    asm volatile("s_waitcnt vmcnt(0)" ::: "memory");
    f32x4 acc = (f32x4){0.f, 0.f, 0.f, 0.f};
#pragma unroll
    for (int it = 0; it < 4; ++it) {
        if (it < 3) {
            og_issue(hy_h, hy_l, Woi_h, Woi_l, arow, brow, kb, it + 1, lc,
                     stw + ((it + 1) & 1) * 4096);
            asm volatile("s_waitcnt vmcnt(8)" ::: "memory");
        } else {
            asm volatile("s_waitcnt vmcnt(0)" ::: "memory");
        }
        __builtin_amdgcn_sched_barrier(0);
        const ushort* W = stw + (it & 1) * 4096;
#pragma unroll
        for (int ks = 0; ks < 2; ++ks) {
            bf16x8 ah = *(const bf16x8*)&W[ks * 512 + lane * 8];
            bf16x8 al = *(const bf16x8*)&W[(2 + ks) * 512 + lane * 8];
            bf16x8 bh = *(const bf16x8*)&W[(4 + ks) * 512 + lane * 8];
            bf16x8 bl = *(const bf16x8*)&W[(6 + ks) * 512 + lane * 8];
            acc = __builtin_amdgcn_mfma_f32_16x16x32_bf16(ah, bh, acc, 0, 0, 0);
            acc = __builtin_amdgcn_mfma_f32_16x16x32_bf16(ah, bl, acc, 0, 0, 0);
            acc = __builtin_amdgcn_mfma_f32_16x16x32_bf16(al, bh, acc, 0, 0, 0);
        }
    }

    const int fc = lane >> 4, fr = lane & 15;
#pragma unroll
    for (int r = 0; r < 4; ++r)
        red[wv * 256 + (fc * 4 + r) * 16 + fr] = acc[r];
    __syncthreads();

    float o = accg + red[bl_ * 16 + tl] + red[256 + bl_ * 16 + tl]
            + red[512 + bl_ * 16 + tl] + red[768 + bl_ * 16 + tl];
    o = tanhf(o);
    outp[(size_t)b * T_ * 1024 + c] = o;
    const int idx = b * 1024 + c;
    const ushort hh = f2bf(o);
    hc_h[idx] = hh;
    hc_l[idx] = f2bf(o - bf2f(hh));
}

// ---------------- conversion / misc ----------------
__global__ __launch_bounds__(256) void cvt2_k(
    const float* __restrict__ in, ushort* __restrict__ hi, ushort* __restrict__ lo, int n4)
{
    const int i = blockIdx.x * 256 + threadIdx.x;
    if (i >= n4) return;
    const float4 v = ((const float4*)in)[i];
    ushort4 h, l;
    h.x = f2bf(v.x); l.x = f2bf(v.x - bf2f(h.x));
    h.y = f2bf(v.y); l.y = f2bf(v.y - bf2f(h.y));
    h.z = f2bf(v.z); l.z = f2bf(v.z - bf2f(h.z));
    h.w = f2bf(v.w); l.w = f2bf(v.w - bf2f(h.w));
    ((ushort4*)hi)[i] = h;
    ((ushort4*)lo)[i] = l;
}

__global__ __launch_bounds__(256) void cvt1_k(
    const float* __restrict__ in, ushort* __restrict__ hi, int n4)
{
    const int i = blockIdx.x * 256 + threadIdx.x;
    if (i >= n4) return;
    const float4 v = ((const float4*)in)[i];
    ushort4 h;
    h.x = f2bf(v.x); h.y = f2bf(v.y); h.z = f2bf(v.z); h.w = f2bf(v.w);
    ((ushort4*)hi)[i] = h;
}

__global__ __launch_bounds__(256) void cvt2s_k(
    const float* __restrict__ in, long instride4, int rowlen4,
    ushort* __restrict__ hi, ushort* __restrict__ lo, int n4)
{
    const int i = blockIdx.x * 256 + threadIdx.x;
    if (i >= n4) return;
    const int r = i / rowlen4, c = i - r * rowlen4;
    const float4 v = ((const float4*)in)[(size_t)r * instride4 + c];
    ushort4 h, l;
    h.x = f2bf(v.x); l.x = f2bf(v.x - bf2f(h.x));
    h.y = f2bf(v.y); l.y = f2bf(v.y - bf2f(h.y));
    h.z = f2bf(v.z); l.z = f2bf(v.z - bf2f(h.z));
    h.w = f2bf(v.w); l.w = f2bf(v.w - bf2f(h.w));
    ((ushort4*)hi)[i] = h;
    ((ushort4*)lo)[i] = l;
}

__global__ void transpose_k(const float* __restrict__ in, float* __restrict__ out)
{
    __shared__ float tile[32][33];
    const int bx = blockIdx.x * 32, by = blockIdx.y * 32;
    const int tx = threadIdx.x, ty = threadIdx.y;   // (32,8)
#pragma unroll
    for (int i = 0; i < 32; i += 8)
        tile[ty + i][tx] = in[(size_t)(by + ty + i) * 1024 + bx + tx];
    __syncthreads();
#pragma unroll
    for (int i = 0; i < 32; i += 8)
        out[(size_t)(bx + ty + i) * 1024 + by + tx] = tile[tx][ty + i];
}

__global__ __launch_bounds__(256) void add_bias_k(
    const float* __restrict__ a, const float* __restrict__ b, float* __restrict__ o, int n)
{
    const int i = blockIdx.x * 256 + threadIdx.x;
    if (i < n) o[i] = a[i] + b[i];
}

__global__ __launch_bounds__(256) void finalize_k(
    const float* __restrict__ out_full, const float* __restrict__ c_buf,
    float* __restrict__ hT, float* __restrict__ cT)
{
    const int idx = blockIdx.x * 256 + threadIdx.x;
    const int b = idx >> 10, j = idx & 1023;
    hT[idx] = out_full[(size_t)b * T_ * H_ + (size_t)(T_ - 1) * H_ + j];
    cT[idx] = c_buf[idx];
}

extern "C" void kernel_launch(void* const* d_in, const int* in_sizes, int n_in,
                              void* d_out, int out_size, void* d_ws, size_t ws_size,
                              hipStream_t stream) {
    const float* target = (const float*)d_in[0];
    const float* h0     = (const float*)d_in[1];
    const float* c0     = (const float*)d_in[2];
    const float* ctx    = (const float*)d_in[3];
    const float* mask   = (const float*)d_in[4];
    const float* W_ih   = (const float*)d_in[5];
    const float* b_ih   = (const float*)d_in[6];
    const float* W_hh   = (const float*)d_in[7];
    const float* b_hh   = (const float*)d_in[8];
    const float* W_in   = (const float*)d_in[9];
    const float* W_ctx  = (const float*)d_in[10];
    const float* W_out  = (const float*)d_in[11];

    float* out = (float*)d_out;
    float* hT  = out + (size_t)B_ * T_ * H_;
    float* cT  = hT + (size_t)B_ * H_;

    // ---- workspace layout ----
    char* p = (char*)d_ws;
    float*  E     = (float*)p;             p += 8388608ull * 4;    // 33.55 MB fp32
    float*  xW    = (float*)p;             p += 8388608ull * 4;    // 33.55 MB
    ushort* Gt_b  = (ushort*)p;            p += 8388608ull * 2;    // 16.78 MB bf16
    ushort* Whh_h = (ushort*)p;            p += 4194304ull * 2;
    ushort* Whh_l = (ushort*)p;            p += 4194304ull * 2;
    ushort* Woi_h = (ushort*)p;            p += 1048576ull * 2;
    ushort* Woi_l = (ushort*)p;            p += 1048576ull * 2;
    float*  bias_sum = (float*)p;          p += 4096ull * 4;
    float*  c_buf = (float*)p;             p += 65536ull * 4;
    ushort* hy_h  = (ushort*)p;            p += 65536ull * 2;
    ushort* hy_l  = (ushort*)p;            p += 65536ull * 2;
    ushort* hc_h  = (ushort*)p;            p += 65536ull * 2;
    ushort* hc_l  = (ushort*)p;            p += 65536ull * 2;
    float*  sc_raw = (float*)p;            p += 8192ull * 4;
    ushort* dcslot = (ushort*)p;           p += 8388608ull * 2;    // dc_b, later tgt planes
    ushort* trans  = (ushort*)p;           p += 20971520ull * 2;   // 41.9 MB transient

    ushort* dc_b   = dcslot;
    // transient phase A: ctx bf16 + W_ctx planes
    ushort* ctx_h  = trans;                            // 16,777,216
    ushort* Wctx_h = trans + 16777216;                 // 2,097,152
    ushort* Wctx_l = trans + 18874368;                 // 2,097,152
    // transient phase B: WinT_f + WinT + Wo1 + Wo2 planes
    float*  WinT_f = (float*)trans;
    ushort* WinT_h = trans + 2097152;
    ushort* WinT_l = trans + 3145728;
    ushort* Wo1_h  = trans + 4194304;
    ushort* Wo1_l  = trans + 5242880;
    ushort* Wo2_h  = trans + 6291456;
    ushort* Wo2_l  = trans + 7340032;
    // transient phase C: target planes (dc slot) + W_ih planes (trans)
    ushort* tgt_h  = dcslot;
    ushort* tgt_l  = dcslot + 2097152;
    ushort* Wih_h  = trans;
    ushort* Wih_l  = trans + 4194304;

    // ---- preamble ----
    add_bias_k<<<16, 256, 0, stream>>>(b_ih, b_hh, bias_sum, 4 * H_);
    cvt2_k<<<4096, 256, 0, stream>>>(W_hh, Whh_h, Whh_l, 1048576);

    // dense_ctx (bf16) = ctx @ W_ctx^T
    cvt1_k<<<16384, 256, 0, stream>>>(ctx, ctx_h, 4194304);
    cvt2_k<<<2048, 256, 0, stream>>>(W_ctx, Wctx_h, Wctx_l, 524288);
    gemm_bf<4, 4, false, true><<<dim3(8, 64), 256, 0, stream>>>(
        ctx_h, nullptr, 2048, Wctx_h, Wctx_l, 2048,
        2048, 1024, nullptr, dc_b, nullptr, nullptr, 0, 0, 0);

    // WinT, Woi = Wo2@W_in, E = dc@W_in (fp32), Gt[b] = Wo1 @ dc[b]^T (bf16)
    transpose_k<<<dim3(32, 32), dim3(32, 8), 0, stream>>>(W_in, WinT_f);
    cvt2_k<<<1024, 256, 0, stream>>>(WinT_f, WinT_h, WinT_l, 262144);
    cvt2s_k<<<1024, 256, 0, stream>>>(W_out, 512, 256, Wo1_h, Wo1_l, 262144);
    cvt2s_k<<<1024, 256, 0, stream>>>(W_out + 1024, 512, 256, Wo2_h, Wo2_l, 262144);
    gemm_bf<4, 4, true, true><<<dim3(8, 8), 256, 0, stream>>>(
        Wo2_h, Wo2_l, 1024, WinT_h, WinT_l, 1024,
        1024, 1024, nullptr, Woi_h, Woi_l, nullptr, 0, 0, 0);
    gemm_bf<4, 4, false, true><<<dim3(8, 64), 256, 0, stream>>>(
        dc_b, nullptr, 1024, WinT_h, WinT_l, 1024,
        1024, 1024, E, nullptr, nullptr, nullptr, 0, 0, 0);
    gemm_bf<4, 4, true, false><<<dim3(1, 8, 64), 256, 0, stream>>>(
        Wo1_h, Wo1_l, 1024, dc_b, nullptr, 1024,
        1024, 128, nullptr, Gt_b, nullptr, nullptr, 0, 131072, 131072);

    // xW = target @ W_ih^T + bias (dc dead now)
    cvt2_k<<<2048, 256, 0, stream>>>(target, tgt_h, tgt_l, 524288);
    cvt2_k<<<4096, 256, 0, stream>>>(W_ih, Wih_h, Wih_l, 1048576);
    gemm_bf<4, 4, true, true><<<dim3(32, 16), 256, 0, stream>>>(
        tgt_h, tgt_l, 1024, Wih_h, Wih_l, 1024,
        1024, 4096, xW, nullptr, nullptr, bias_sum, 0, 0, 0);

    // loop state
    cvt2_k<<<64, 256, 0, stream>>>(h0, hc_h, hc_l, 16384);
    hipMemcpyAsync(c_buf, c0, sizeof(float) * B_ * H_, hipMemcpyDeviceToDevice, stream);

    for (int t = 0; t < T_; ++t) {
        gates_cell<<<dim3(64, 4), 256, 0, stream>>>(
            hc_h, hc_l, Whh_h, Whh_l, xW + (size_t)t * 4096, c_buf, hy_h, hy_l);
        scores_k<<<dim3(64, 4), 256, 0, stream>>>(E, hy_h, hy_l, mask, sc_raw);
        outg_k<<<dim3(64, 4), 256, 0, stream>>>(
            sc_raw, Gt_b, hy_h, hy_l, Woi_h, Woi_l,
            out + (size_t)t * H_, hc_h, hc_l);
    }

    finalize_k<<<256, 256, 0, stream>>>(out, c_buf, hT, cT);
}

// Round 12
// 1289.993 us; speedup vs baseline: 2.6336x; 1.0376x over previous
//
#include <hip/hip_runtime.h>
#include <cstddef>

#define B_ 64
#define T_ 32
#define S_ 128
#define IN_ 1024
#define H_ 1024

typedef __bf16 bf16x8 __attribute__((ext_vector_type(8)));
typedef float f32x4 __attribute__((ext_vector_type(4)));

__device__ __forceinline__ float sigmoidf_(float x) { return 1.0f / (1.0f + expf(-x)); }

__device__ __forceinline__ ushort f2bf(float x) {
    unsigned u = __builtin_bit_cast(unsigned, x);
    unsigned r = (u + 0x7fffu + ((u >> 16) & 1u)) >> 16;
    return (ushort)r;
}
__device__ __forceinline__ float bf2f(ushort h) {
    unsigned u = ((unsigned)h) << 16;
    return __builtin_bit_cast(float, u);
}
__device__ __forceinline__ ushort f2h(float x) {
    return __builtin_bit_cast(ushort, (_Float16)x);
}
__device__ __forceinline__ float h2f(ushort h) {
    return (float)__builtin_bit_cast(_Float16, h);
}

// async global->LDS, 16B per lane; lds dest wave-uniform (HW adds lane*16).
__device__ __forceinline__ void gll16(const ushort* g, ushort* l) {
    __builtin_amdgcn_global_load_lds(
        (const __attribute__((address_space(1))) void*)g,
        (__attribute__((address_space(3))) void*)l,
        16, 0, 0);
}

// ---------------- big-GEMM (preamble): C = A @ B^T, split-bf16 planes ----------
// Optional blockIdx.z batching via element strides Az/Bz/Cz.
// out modes: Cf -> fp32 (+bias); Cbl -> hi/lo planes; Cbh + h16 -> fp16; Cbh -> bf16.
// Bijective XCD swizzle on the flattened (y,x) grid when nwg%8==0 (tile remap only).
template<int FM, int FN, bool ALO, bool BLO>
__global__ __launch_bounds__(256) void gemm_bf(
    const ushort* __restrict__ Ah_g, const ushort* __restrict__ Al_g, long lda,
    const ushort* __restrict__ Bh_g, const ushort* __restrict__ Bl_g, long ldb,
    int K, int N,
    float* __restrict__ Cf, ushort* __restrict__ Cbh, ushort* __restrict__ Cbl,
    const float* __restrict__ bias,
    long Az, long Bz, long Cz, int h16)
{
    constexpr int NSA = 4 * FM;
    constexpr int NSB = 4 * FN;
    constexpr int OAL = NSA;
    constexpr int OBH = NSA * (ALO ? 2 : 1);
    constexpr int OBL = OBH + NSB;
    constexpr int NST = OBH + NSB * (BLO ? 2 : 1);
    __shared__ ushort lds[NST * 512];

    const long z = blockIdx.z;
    Ah_g += z * Az; if (ALO) Al_g += z * Az;
    Bh_g += z * Bz; if (BLO) Bl_g += z * Bz;
    if (Cf) Cf += z * Cz;
    if (Cbh) Cbh += z * Cz;
    if (Cbl) Cbl += z * Cz;

    // XCD-aware bijective swizzle (m204 formula, nwg%8==0 case)
    int flat = blockIdx.y * gridDim.x + blockIdx.x;
    const int nwg = gridDim.x * gridDim.y;
    if ((nwg & 7) == 0) {
        const int q = nwg >> 3;
        flat = (flat & 7) * q + (flat >> 3);
    }
    const int bx = flat % gridDim.x;
    const int by = flat / gridDim.x;

    const int tid = threadIdx.x;
    const int lane = tid & 63, wv = tid >> 6;
    const int wm = wv >> 1, wn = wv & 1;
    const int m0 = by * (FM * 32), n0 = bx * (FN * 32);
    const int lr = lane & 15, lc = lane >> 4;

    f32x4 acc[FM][FN];
#pragma unroll
    for (int i = 0; i < FM; ++i)
#pragma unroll
        for (int j = 0; j < FN; ++j) acc[i][j] = (f32x4){0.f, 0.f, 0.f, 0.f};

    for (int k0 = 0; k0 < K; k0 += 64) {
#pragma unroll
        for (int q = 0; q < NST / 4; ++q) {
            const int si = wv * (NST / 4) + q;
            const ushort* P; long ld; int row0; int st;
            if (si < OBH) {
                if (ALO && si >= NSA) { P = Al_g; st = si - NSA; }
                else                  { P = Ah_g; st = si; }
                ld = lda; row0 = m0;
            } else {
                const int sj = si - OBH;
                if (BLO && sj >= NSB) { P = Bl_g; st = sj - NSB; }
                else                  { P = Bh_g; st = sj; }
                ld = ldb; row0 = n0;
            }
            const int row = ((st >> 1) << 4) + lr;
            const int kc = ((st & 1) << 5) + (lc << 3);
            gll16(P + (size_t)(row0 + row) * ld + k0 + kc, &lds[si * 512]);
        }
        __syncthreads();
#pragma unroll
        for (int ks = 0; ks < 2; ++ks) {
            bf16x8 ah[FM], al[FM], bh[FN], bl[FN];
#pragma unroll
            for (int i = 0; i < FM; ++i) {
                const int st = (wm * FM + i) * 2 + ks;
                ah[i] = *(const bf16x8*)&lds[st * 512 + lane * 8];
                if (ALO) al[i] = *(const bf16x8*)&lds[(OAL + st) * 512 + lane * 8];
            }
#pragma unroll
            for (int j = 0; j < FN; ++j) {
                const int st = (wn * FN + j) * 2 + ks;
                bh[j] = *(const bf16x8*)&lds[(OBH + st) * 512 + lane * 8];
                if (BLO) bl[j] = *(const bf16x8*)&lds[(OBL + st) * 512 + lane * 8];
            }
#pragma unroll
            for (int i = 0; i < FM; ++i)
#pragma unroll
                for (int j = 0; j < FN; ++j) {
                    acc[i][j] = __builtin_amdgcn_mfma_f32_16x16x32_bf16(ah[i], bh[j], acc[i][j], 0, 0, 0);
                    if (BLO) acc[i][j] = __builtin_amdgcn_mfma_f32_16x16x32_bf16(ah[i], bl[j], acc[i][j], 0, 0, 0);
                    if (ALO) acc[i][j] = __builtin_amdgcn_mfma_f32_16x16x32_bf16(al[i], bh[j], acc[i][j], 0, 0, 0);
                }
        }
        __syncthreads();
    }

    const int fr = lane & 15, fc = lane >> 4;
#pragma unroll
    for (int i = 0; i < FM; ++i)
#pragma unroll
        for (int j = 0; j < FN; ++j) {
            const int mb = m0 + wm * FM * 16 + i * 16 + fc * 4;
            const int nb = n0 + wn * FN * 16 + j * 16 + fr;
            const float bv = bias ? bias[nb] : 0.f;
#pragma unroll
            for (int r = 0; r < 4; ++r) {
                const float v = acc[i][j][r] + bv;
                const size_t o = (size_t)(mb + r) * N + nb;
                if (Cf) Cf[o] = v;
                else if (Cbl) { const ushort hh = f2bf(v); Cbh[o] = hh; Cbl[o] = f2bf(v - bf2f(hh)); }
                else if (h16) Cbh[o] = f2h(v);
                else Cbh[o] = f2bf(v);
            }
        }
}

// ---------------- per-step kernels ----------------

__device__ __forceinline__ void gc_issue(
    const ushort* __restrict__ hc_h, const ushort* __restrict__ hc_l,
    const ushort* __restrict__ Whh_h, const ushort* __restrict__ Whh_l,
    int jc, int mb, int wv, int lr, int lc, int k0, ushort* dst)
{
#pragma unroll
    for (int q = 0; q < 5; ++q) {
        const int si = wv * 5 + q;
        const ushort* P; size_t rowoff; int ks;
        if (si < 4) {
            P = (si < 2) ? hc_h : hc_l;
            ks = si & 1;
            rowoff = (size_t)(mb * 16 + lr) * 1024;
        } else {
            const int sj = si - 4;
            P = (sj < 8) ? Whh_h : Whh_l;
            const int g = (sj & 7) >> 1;
            ks = sj & 1;
            rowoff = (size_t)(g * 1024 + jc * 16 + lr) * 1024;
        }
        gll16(P + rowoff + k0 + ks * 32 + lc * 8, dst + si * 512);
    }
}

// K1: gates + LSTM cell. grid (64 colgrp, 4 batchgrp); wave g = gate g.
// 3-buffer pipeline: raw s_barrier + counted vmcnt(5). (round-7 proven)
__global__ __launch_bounds__(256) void gates_cell(
    const ushort* __restrict__ hc_h, const ushort* __restrict__ hc_l,
    const ushort* __restrict__ Whh_h, const ushort* __restrict__ Whh_l,
    const float* __restrict__ xWt,
    float* __restrict__ c_buf, ushort* __restrict__ hy_h, ushort* __restrict__ hy_l)
{
    __shared__ ushort lds[3][10240];   // 60 KB
    __shared__ float gl[1024];         // 4 KB
    const int jc = blockIdx.x;
    const int mb = blockIdx.y;
    const int tid = threadIdx.x, lane = tid & 63, wv = tid >> 6;
    const int lr = lane & 15, lc = lane >> 4;

    f32x4 acc = (f32x4){0.f, 0.f, 0.f, 0.f};

    gc_issue(hc_h, hc_l, Whh_h, Whh_l, jc, mb, wv, lr, lc, 0, &lds[0][0]);
#pragma unroll
    for (int it = 0; it < 16; ++it) {
        if (it < 15) {
            gc_issue(hc_h, hc_l, Whh_h, Whh_l, jc, mb, wv, lr, lc,
                     (it + 1) * 64, &lds[(it + 1) % 3][0]);
            asm volatile("s_waitcnt vmcnt(5)" ::: "memory");
        } else {
            asm volatile("s_waitcnt vmcnt(0)" ::: "memory");
        }
        __builtin_amdgcn_s_barrier();
        __builtin_amdgcn_sched_barrier(0);
        const ushort* L = &lds[it % 3][0];
#pragma unroll
        for (int ks = 0; ks < 2; ++ks) {
            bf16x8 ah = *(const bf16x8*)&L[ks * 512 + lane * 8];
            bf16x8 al = *(const bf16x8*)&L[(2 + ks) * 512 + lane * 8];
            bf16x8 bh = *(const bf16x8*)&L[(4 + wv * 2 + ks) * 512 + lane * 8];
            bf16x8 bl = *(const bf16x8*)&L[(12 + wv * 2 + ks) * 512 + lane * 8];
            acc = __builtin_amdgcn_mfma_f32_16x16x32_bf16(ah, bh, acc, 0, 0, 0);
            acc = __builtin_amdgcn_mfma_f32_16x16x32_bf16(ah, bl, acc, 0, 0, 0);
            acc = __builtin_amdgcn_mfma_f32_16x16x32_bf16(al, bh, acc, 0, 0, 0);
        }
    }

    const int fr = lane & 15, fc = lane >> 4;
#pragma unroll
    for (int r = 0; r < 4; ++r)
        gl[wv * 256 + (fc * 4 + r) * 16 + fr] = acc[r];
    __syncthreads();

    const int bl_ = tid >> 4, cl = tid & 15;
    const int b = mb * 16 + bl_, col = jc * 16 + cl;
    const float* xw = xWt + (size_t)b * T_ * 4096;
    const float gi = gl[bl_ * 16 + cl]        + xw[col];
    const float gf = gl[256 + bl_ * 16 + cl]  + xw[1024 + col];
    const float gg = gl[512 + bl_ * 16 + cl]  + xw[2048 + col];
    const float go = gl[768 + bl_ * 16 + cl]  + xw[3072 + col];
    const int idx = b * 1024 + col;
    const float cn = sigmoidf_(gf) * c_buf[idx] + sigmoidf_(gi) * tanhf(gg);
    c_buf[idx] = cn;
    const float h = sigmoidf_(go) * tanhf(cn);
    const ushort hh = f2bf(h);
    hy_h[idx] = hh;
    hy_l[idx] = f2bf(h - bf2f(hh));
}

// K2: raw scores from fp16 E. grid (64 b, 4 sgroup of 32).
// sc_raw[b,s] = E[b,s,:]·hy[b,:] - neg.
__global__ __launch_bounds__(256) void scores_k(
    const ushort* __restrict__ E,
    const ushort* __restrict__ hy_h, const ushort* __restrict__ hy_l,
    const float* __restrict__ mask, float* __restrict__ sc_raw)
{
    const int b = blockIdx.x, sg = blockIdx.y;
    const int tid = threadIdx.x, lane = tid & 63, wv = tid >> 6;
    __shared__ alignas(16) float sinp[IN_];
#pragma unroll
    for (int i = 0; i < 4; ++i) {
        const int j = tid + i * 256;
        sinp[j] = bf2f(hy_h[b * 1024 + j]) + bf2f(hy_l[b * 1024 + j]);
    }
    __syncthreads();
#pragma unroll
    for (int r = 0; r < 8; ++r) {
        const int s = sg * 32 + wv * 8 + r;
        const ushort* row = E + ((size_t)b * S_ + s) * 1024;
        float sum = 0.f;
#pragma unroll
        for (int it = 0; it < 2; ++it) {
            const int e = it * 512 + lane * 8;
            const uint4 v = *(const uint4*)(row + e);
            const float4 w0 = *(const float4*)&sinp[e];
            const float4 w1 = *(const float4*)&sinp[e + 4];
            sum += h2f(v.x & 0xffff) * w0.x + h2f(v.x >> 16) * w0.y
                 + h2f(v.y & 0xffff) * w0.z + h2f(v.y >> 16) * w0.w
                 + h2f(v.z & 0xffff) * w1.x + h2f(v.z >> 16) * w1.y
                 + h2f(v.w & 0xffff) * w1.z + h2f(v.w >> 16) * w1.w;
        }
#pragma unroll
        for (int off = 32; off > 0; off >>= 1) sum += __shfl_xor(sum, off);
        if (lane == 0)
            sc_raw[b * S_ + s] = sum - (1.0f - mask[(size_t)b * S_ + s]) * 100000.0f;
    }
}

__device__ __forceinline__ void og_issue(
    const ushort* __restrict__ hy_h, const ushort* __restrict__ hy_l,
    const ushort* __restrict__ Woi_h, const ushort* __restrict__ Woi_l,
    size_t arow, size_t brow, int kb, int it, int lc, ushort* dst)
{
    const int k0 = kb + it * 64 + lc * 8;
    gll16(hy_h + arow + k0,       dst);
    gll16(hy_h + arow + k0 + 32,  dst + 512);
    gll16(hy_l + arow + k0,       dst + 1024);
    gll16(hy_l + arow + k0 + 32,  dst + 1536);
    gll16(Woi_h + brow + k0,      dst + 2048);
    gll16(Woi_h + brow + k0 + 32, dst + 2560);
    gll16(Woi_l + brow + k0,      dst + 3072);
    gll16(Woi_l + brow + k0 + 32, dst + 3584);
}

// K3: out = tanh( softmax(sc) @ Gt + hy @ Woi^T ). grid (64 colgrp, 4 batchgrp).
// Softmax per 16-lane group (redundant, deterministic). G-part: bf16 Gt stream.
// MFMA part: wave-private K-split dbuf, counted vmcnt. (round-11 proven)
__global__ __launch_bounds__(256) void outg_k(
    const float* __restrict__ sc_raw,
    const ushort* __restrict__ Gt_b,
    const ushort* __restrict__ hy_h, const ushort* __restrict__ hy_l,
    const ushort* __restrict__ Woi_h, const ushort* __restrict__ Woi_l,
    float* __restrict__ outp, ushort* __restrict__ hc_h, ushort* __restrict__ hc_l)
{
    __shared__ ushort st[4][2][4096];   // 64 KB
    __shared__ float aS[16][128];       // 8 KB
    __shared__ float red[1024];         // 4 KB
    const int nc = blockIdx.x, mb = blockIdx.y;
    const int tid = threadIdx.x, lane = tid & 63, wv = tid >> 6;
    const int lr = lane & 15, lc = lane >> 4;
    const int kb = wv * 256;
    const size_t arow = (size_t)(mb * 16 + lr) * 1024;
    const size_t brow = (size_t)(nc * 16 + lr) * 1024;
    ushort* stw = &st[wv][0][0];

    og_issue(hy_h, hy_l, Woi_h, Woi_l, arow, brow, kb, 0, lc, stw);

    // softmax for this block's 16 batches (16 lanes per batch, in-wave)
    const int bl_ = tid >> 4, tl = tid & 15;
    const int b = mb * 16 + bl_;
    float v[8], mx = -3.4e38f;
#pragma unroll
    for (int i = 0; i < 8; ++i) {
        v[i] = sc_raw[b * S_ + tl * 8 + i];
        mx = fmaxf(mx, v[i]);
    }
#pragma unroll
    for (int off = 1; off < 16; off <<= 1) mx = fmaxf(mx, __shfl_xor(mx, off));
    float sm = 0.f;
#pragma unroll
    for (int i = 0; i < 8; ++i) { v[i] = expf(v[i] - mx); sm += v[i]; }
#pragma unroll
    for (int off = 1; off < 16; off <<= 1) sm += __shfl_xor(sm, off);
    const float inv = 1.0f / sm;
#pragma unroll
    for (int i = 0; i < 8; ++i) aS[bl_][tl * 8 + i] = v[i] * inv;
    asm volatile("s_waitcnt lgkmcnt(0)" ::: "memory");

    // G part: a @ Gt[b][col][:]  (Gt bf16 single plane)
    const int c = nc * 16 + tl;
    const ushort* gt = Gt_b + ((size_t)b * 1024 + c) * 128;
    float accg = 0.f;
#pragma unroll
    for (int i = 0; i < 16; ++i) {
        const uint4 g4 = *(const uint4*)(gt + i * 8);
        const float* a = &aS[bl_][i * 8];
        accg += a[0] * bf2f(g4.x & 0xffff) + a[1] * bf2f(g4.x >> 16)
              + a[2] * bf2f(g4.y & 0xffff) + a[3] * bf2f(g4.y >> 16)
              + a[4] * bf2f(g4.z & 0xffff) + a[5] * bf2f(g4.z >> 16)
              + a[6] * bf2f(g4.w & 0xffff) + a[7] * bf2f(g4.w >> 16);
    }

    // MFMA part: hy @ Woi^T, wave-private K slice, dbuf counted vmcnt
    asm volatile("s_waitcnt vmcnt(0)" ::: "memory");
    f32x4 acc = (f32x4){0.f, 0.f, 0.f, 0.f};
#pragma unroll
    for (int it = 0; it < 4; ++it) {
        if (it < 3) {
            og_issue(hy_h, hy_l, Woi_h, Woi_l, arow, brow, kb, it + 1, lc,
                     stw + ((it + 1) & 1) * 4096);
            asm volatile("s_waitcnt vmcnt(8)" ::: "memory");
        } else {
            asm volatile("s_waitcnt vmcnt(0)" ::: "memory");
        }
        __builtin_amdgcn_sched_barrier(0);
        const ushort* W = stw + (it & 1) * 4096;
#pragma unroll
        for (int ks = 0; ks < 2; ++ks) {
            bf16x8 ah = *(const bf16x8*)&W[ks * 512 + lane * 8];
            bf16x8 al = *(const bf16x8*)&W[(2 + ks) * 512 + lane * 8];
            bf16x8 bh = *(const bf16x8*)&W[(4 + ks) * 512 + lane * 8];
            bf16x8 bl = *(const bf16x8*)&W[(6 + ks) * 512 + lane * 8];
            acc = __builtin_amdgcn_mfma_f32_16x16x32_bf16(ah, bh, acc, 0, 0, 0);
            acc = __builtin_amdgcn_mfma_f32_16x16x32_bf16(ah, bl, acc, 0, 0, 0);
            acc = __builtin_amdgcn_mfma_f32_16x16x32_bf16(al, bh, acc, 0, 0, 0);
        }
    }

    const int fc = lane >> 4, fr = lane & 15;
#pragma unroll
    for (int r = 0; r < 4; ++r)
        red[wv * 256 + (fc * 4 + r) * 16 + fr] = acc[r];
    __syncthreads();

    float o = accg + red[bl_ * 16 + tl] + red[256 + bl_ * 16 + tl]
            + red[512 + bl_ * 16 + tl] + red[768 + bl_ * 16 + tl];
    o = tanhf(o);
    outp[(size_t)b * T_ * 1024 + c] = o;
    const int idx = b * 1024 + c;
    const ushort hh = f2bf(o);
    hc_h[idx] = hh;
    hc_l[idx] = f2bf(o - bf2f(hh));
}

// ---------------- conversion / misc ----------------
__global__ __launch_bounds__(256) void cvt2_k(
    const float* __restrict__ in, ushort* __restrict__ hi, ushort* __restrict__ lo, int n4)
{
    const int i = blockIdx.x * 256 + threadIdx.x;
    if (i >= n4) return;
    const float4 v = ((const float4*)in)[i];
    ushort4 h, l;
    h.x = f2bf(v.x); l.x = f2bf(v.x - bf2f(h.x));
    h.y = f2bf(v.y); l.y = f2bf(v.y - bf2f(h.y));
    h.z = f2bf(v.z); l.z = f2bf(v.z - bf2f(h.z));
    h.w = f2bf(v.w); l.w = f2bf(v.w - bf2f(h.w));
    ((ushort4*)hi)[i] = h;
    ((ushort4*)lo)[i] = l;
}

__global__ __launch_bounds__(256) void cvt1_k(
    const float* __restrict__ in, ushort* __restrict__ hi, int n4)
{
    const int i = blockIdx.x * 256 + threadIdx.x;
    if (i >= n4) return;
    const float4 v = ((const float4*)in)[i];
    ushort4 h;
    h.x = f2bf(v.x); h.y = f2bf(v.y); h.z = f2bf(v.z); h.w = f2bf(v.w);
    ((ushort4*)hi)[i] = h;
}

__global__ __launch_bounds__(256) void cvt2s_k(
    const float* __restrict__ in, long instride4, int rowlen4,
    ushort* __restrict__ hi, ushort* __restrict__ lo, int n4)
{
    const int i = blockIdx.x * 256 + threadIdx.x;
    if (i >= n4) return;
    const int r = i / rowlen4, c = i - r * rowlen4;
    const float4 v = ((const float4*)in)[(size_t)r * instride4 + c];
    ushort4 h, l;
    h.x = f2bf(v.x); l.x = f2bf(v.x - bf2f(h.x));
    h.y = f2bf(v.y); l.y = f2bf(v.y - bf2f(h.y));
    h.z = f2bf(v.z); l.z = f2bf(v.z - bf2f(h.z));
    h.w = f2bf(v.w); l.w = f2bf(v.w - bf2f(h.w));
    ((ushort4*)hi)[i] = h;
    ((ushort4*)lo)[i] = l;
}

__global__ void transpose_k(const float* __restrict__ in, float* __restrict__ out)
{
    __shared__ float tile[32][33];
    const int bx = blockIdx.x * 32, by = blockIdx.y * 32;
    const int tx = threadIdx.x, ty = threadIdx.y;   // (32,8)
#pragma unroll
    for (int i = 0; i < 32; i += 8)
        tile[ty + i][tx] = in[(size_t)(by + ty + i) * 1024 + bx + tx];
    __syncthreads();
#pragma unroll
    for (int i = 0; i < 32; i += 8)
        out[(size_t)(bx + ty + i) * 1024 + by + tx] = tile[tx][ty + i];
}

__global__ __launch_bounds__(256) void add_bias_k(
    const float* __restrict__ a, const float* __restrict__ b, float* __restrict__ o, int n)
{
    const int i = blockIdx.x * 256 + threadIdx.x;
    if (i < n) o[i] = a[i] + b[i];
}

__global__ __launch_bounds__(256) void finalize_k(
    const float* __restrict__ out_full, const float* __restrict__ c_buf,
    float* __restrict__ hT, float* __restrict__ cT)
{
    const int idx = blockIdx.x * 256 + threadIdx.x;
    const int b = idx >> 10, j = idx & 1023;
    hT[idx] = out_full[(size_t)b * T_ * H_ + (size_t)(T_ - 1) * H_ + j];
    cT[idx] = c_buf[idx];
}

extern "C" void kernel_launch(void* const* d_in, const int* in_sizes, int n_in,
                              void* d_out, int out_size, void* d_ws, size_t ws_size,
                              hipStream_t stream) {
    const float* target = (const float*)d_in[0];
    const float* h0     = (const float*)d_in[1];
    const float* c0     = (const float*)d_in[2];
    const float* ctx    = (const float*)d_in[3];
    const float* mask   = (const float*)d_in[4];
    const float* W_ih   = (const float*)d_in[5];
    const float* b_ih   = (const float*)d_in[6];
    const float* W_hh   = (const float*)d_in[7];
    const float* b_hh   = (const float*)d_in[8];
    const float* W_in   = (const float*)d_in[9];
    const float* W_ctx  = (const float*)d_in[10];
    const float* W_out  = (const float*)d_in[11];

    float* out = (float*)d_out;
    float* hT  = out + (size_t)B_ * T_ * H_;
    float* cT  = hT + (size_t)B_ * H_;

    // ---- workspace layout ----
    char* p = (char*)d_ws;
    ushort* E_h   = (ushort*)p;            p += 8388608ull * 2;    // 16.78 MB fp16
    float*  xW    = (float*)p;             p += 8388608ull * 4;    // 33.55 MB
    ushort* Gt_b  = (ushort*)p;            p += 8388608ull * 2;    // 16.78 MB bf16
    ushort* Whh_h = (ushort*)p;            p += 4194304ull * 2;
    ushort* Whh_l = (ushort*)p;            p += 4194304ull * 2;
    ushort* Woi_h = (ushort*)p;            p += 1048576ull * 2;
    ushort* Woi_l = (ushort*)p;            p += 1048576ull * 2;
    float*  bias_sum = (float*)p;          p += 4096ull * 4;
    float*  c_buf = (float*)p;             p += 65536ull * 4;
    ushort* hy_h  = (ushort*)p;            p += 65536ull * 2;
    ushort* hy_l  = (ushort*)p;            p += 65536ull * 2;
    ushort* hc_h  = (ushort*)p;            p += 65536ull * 2;
    ushort* hc_l  = (ushort*)p;            p += 65536ull * 2;
    float*  sc_raw = (float*)p;            p += 8192ull * 4;
    ushort* dcslot = (ushort*)p;           p += 8388608ull * 2;    // dc_b, later tgt planes
    ushort* trans  = (ushort*)p;           p += 20971520ull * 2;   // 41.9 MB transient

    ushort* dc_b   = dcslot;
    // transient phase A: ctx bf16 + W_ctx planes
    ushort* ctx_h  = trans;                            // 16,777,216
    ushort* Wctx_h = trans + 16777216;                 // 2,097,152
    ushort* Wctx_l = trans + 18874368;                 // 2,097,152
    // transient phase B: WinT_f + WinT + Wo1 + Wo2 planes
    float*  WinT_f = (float*)trans;
    ushort* WinT_h = trans + 2097152;
    ushort* WinT_l = trans + 3145728;
    ushort* Wo1_h  = trans + 4194304;
    ushort* Wo1_l  = trans + 5242880;
    ushort* Wo2_h  = trans + 6291456;
    ushort* Wo2_l  = trans + 7340032;
    // transient phase C: target planes (dc slot) + W_ih planes (trans)
    ushort* tgt_h  = dcslot;
    ushort* tgt_l  = dcslot + 2097152;
    ushort* Wih_h  = trans;
    ushort* Wih_l  = trans + 4194304;

    // ---- preamble ----
    add_bias_k<<<16, 256, 0, stream>>>(b_ih, b_hh, bias_sum, 4 * H_);
    cvt2_k<<<4096, 256, 0, stream>>>(W_hh, Whh_h, Whh_l, 1048576);

    // dense_ctx (bf16) = ctx @ W_ctx^T
    cvt1_k<<<16384, 256, 0, stream>>>(ctx, ctx_h, 4194304);
    cvt2_k<<<2048, 256, 0, stream>>>(W_ctx, Wctx_h, Wctx_l, 524288);
    gemm_bf<4, 4, false, true><<<dim3(8, 64), 256, 0, stream>>>(
        ctx_h, nullptr, 2048, Wctx_h, Wctx_l, 2048,
        2048, 1024, nullptr, dc_b, nullptr, nullptr, 0, 0, 0, 0);

    // WinT, Woi = Wo2@W_in, E = dc@W_in (fp16), Gt[b] = Wo1 @ dc[b]^T (bf16)
    transpose_k<<<dim3(32, 32), dim3(32, 8), 0, stream>>>(W_in, WinT_f);
    cvt2_k<<<1024, 256, 0, stream>>>(WinT_f, WinT_h, WinT_l, 262144);
    cvt2s_k<<<1024, 256, 0, stream>>>(W_out, 512, 256, Wo1_h, Wo1_l, 262144);
    cvt2s_k<<<1024, 256, 0, stream>>>(W_out + 1024, 512, 256, Wo2_h, Wo2_l, 262144);
    gemm_bf<4, 4, true, true><<<dim3(8, 8), 256, 0, stream>>>(
        Wo2_h, Wo2_l, 1024, WinT_h, WinT_l, 1024,
        1024, 1024, nullptr, Woi_h, Woi_l, nullptr, 0, 0, 0, 0);
    gemm_bf<4, 4, false, true><<<dim3(8, 64), 256, 0, stream>>>(
        dc_b, nullptr, 1024, WinT_h, WinT_l, 1024,
        1024, 1024, nullptr, E_h, nullptr, nullptr, 0, 0, 0, 1);
    gemm_bf<4, 4, true, false><<<dim3(1, 8, 64), 256, 0, stream>>>(
        Wo1_h, Wo1_l, 1024, dc_b, nullptr, 1024,
        1024, 128, nullptr, Gt_b, nullptr, nullptr, 0, 131072, 131072, 0);

    // xW = target @ W_ih^T + bias (dc dead now)
    cvt2_k<<<2048, 256, 0, stream>>>(target, tgt_h, tgt_l, 524288);
    cvt2_k<<<4096, 256, 0, stream>>>(W_ih, Wih_h, Wih_l, 1048576);
    gemm_bf<4, 4, true, true><<<dim3(32, 16), 256, 0, stream>>>(
        tgt_h, tgt_l, 1024, Wih_h, Wih_l, 1024,
        1024, 4096, xW, nullptr, nullptr, bias_sum, 0, 0, 0, 0);

    // loop state
    cvt2_k<<<64, 256, 0, stream>>>(h0, hc_h, hc_l, 16384);
    hipMemcpyAsync(c_buf, c0, sizeof(float) * B_ * H_, hipMemcpyDeviceToDevice, stream);

    for (int t = 0; t < T_; ++t) {
        gates_cell<<<dim3(64, 4), 256, 0, stream>>>(
            hc_h, hc_l, Whh_h, Whh_l, xW + (size_t)t * 4096, c_buf, hy_h, hy_l);
        scores_k<<<dim3(64, 4), 256, 0, stream>>>(E_h, hy_h, hy_l, mask, sc_raw);
        outg_k<<<dim3(64, 4), 256, 0, stream>>>(
            sc_raw, Gt_b, hy_h, hy_l, Woi_h, Woi_l,
            out + (size_t)t * H_, hc_h, hc_l);
    }

    finalize_k<<<256, 256, 0, stream>>>(out, c_buf, hT, cT);
}

// Round 13
// 1165.698 us; speedup vs baseline: 2.9144x; 1.1066x over previous
//
#include <hip/hip_runtime.h>
#include <cstddef>

#define B_ 64
#define T_ 32
#define S_ 128
#define IN_ 1024
#define H_ 1024

typedef __bf16 bf16x8 __attribute__((ext_vector_type(8)));
typedef _Float16 f16x8 __attribute__((ext_vector_type(8)));
typedef float f32x4 __attribute__((ext_vector_type(4)));

__device__ __forceinline__ float sigmoidf_(float x) { return 1.0f / (1.0f + expf(-x)); }

__device__ __forceinline__ ushort f2bf(float x) {
    unsigned u = __builtin_bit_cast(unsigned, x);
    unsigned r = (u + 0x7fffu + ((u >> 16) & 1u)) >> 16;
    return (ushort)r;
}
__device__ __forceinline__ float bf2f(ushort h) {
    unsigned u = ((unsigned)h) << 16;
    return __builtin_bit_cast(float, u);
}
__device__ __forceinline__ ushort f2h(float x) {
    return __builtin_bit_cast(ushort, (_Float16)x);
}
__device__ __forceinline__ float h2f(ushort h) {
    return (float)__builtin_bit_cast(_Float16, h);
}

// async global->LDS, 16B per lane; lds dest wave-uniform (HW adds lane*16).
__device__ __forceinline__ void gll16(const ushort* g, ushort* l) {
    __builtin_amdgcn_global_load_lds(
        (const __attribute__((address_space(1))) void*)g,
        (__attribute__((address_space(3))) void*)l,
        16, 0, 0);
}

// ---------------- big-GEMM (preamble): C = A @ B^T, split-bf16 planes ----------
// out modes: Cf -> fp32 (+bias); Cbl -> hi/lo planes; Cbh + h16 -> fp16; Cbh -> bf16.
// Bijective XCD swizzle when nwg%8==0 (round-12 proven).
template<int FM, int FN, bool ALO, bool BLO>
__global__ __launch_bounds__(256) void gemm_bf(
    const ushort* __restrict__ Ah_g, const ushort* __restrict__ Al_g, long lda,
    const ushort* __restrict__ Bh_g, const ushort* __restrict__ Bl_g, long ldb,
    int K, int N,
    float* __restrict__ Cf, ushort* __restrict__ Cbh, ushort* __restrict__ Cbl,
    const float* __restrict__ bias,
    long Az, long Bz, long Cz, int h16)
{
    constexpr int NSA = 4 * FM;
    constexpr int NSB = 4 * FN;
    constexpr int OAL = NSA;
    constexpr int OBH = NSA * (ALO ? 2 : 1);
    constexpr int OBL = OBH + NSB;
    constexpr int NST = OBH + NSB * (BLO ? 2 : 1);
    __shared__ ushort lds[NST * 512];

    const long z = blockIdx.z;
    Ah_g += z * Az; if (ALO) Al_g += z * Az;
    Bh_g += z * Bz; if (BLO) Bl_g += z * Bz;
    if (Cf) Cf += z * Cz;
    if (Cbh) Cbh += z * Cz;
    if (Cbl) Cbl += z * Cz;

    int flat = blockIdx.y * gridDim.x + blockIdx.x;
    const int nwg = gridDim.x * gridDim.y;
    if ((nwg & 7) == 0) {
        const int q = nwg >> 3;
        flat = (flat & 7) * q + (flat >> 3);
    }
    const int bx = flat % gridDim.x;
    const int by = flat / gridDim.x;

    const int tid = threadIdx.x;
    const int lane = tid & 63, wv = tid >> 6;
    const int wm = wv >> 1, wn = wv & 1;
    const int m0 = by * (FM * 32), n0 = bx * (FN * 32);
    const int lr = lane & 15, lc = lane >> 4;

    f32x4 acc[FM][FN];
#pragma unroll
    for (int i = 0; i < FM; ++i)
#pragma unroll
        for (int j = 0; j < FN; ++j) acc[i][j] = (f32x4){0.f, 0.f, 0.f, 0.f};

    for (int k0 = 0; k0 < K; k0 += 64) {
#pragma unroll
        for (int q = 0; q < NST / 4; ++q) {
            const int si = wv * (NST / 4) + q;
            const ushort* P; long ld; int row0; int st;
            if (si < OBH) {
                if (ALO && si >= NSA) { P = Al_g; st = si - NSA; }
                else                  { P = Ah_g; st = si; }
                ld = lda; row0 = m0;
            } else {
                const int sj = si - OBH;
                if (BLO && sj >= NSB) { P = Bl_g; st = sj - NSB; }
                else                  { P = Bh_g; st = sj; }
                ld = ldb; row0 = n0;
            }
            const int row = ((st >> 1) << 4) + lr;
            const int kc = ((st & 1) << 5) + (lc << 3);
            gll16(P + (size_t)(row0 + row) * ld + k0 + kc, &lds[si * 512]);
        }
        __syncthreads();
#pragma unroll
        for (int ks = 0; ks < 2; ++ks) {
            bf16x8 ah[FM], al[FM], bh[FN], bl[FN];
#pragma unroll
            for (int i = 0; i < FM; ++i) {
                const int st = (wm * FM + i) * 2 + ks;
                ah[i] = *(const bf16x8*)&lds[st * 512 + lane * 8];
                if (ALO) al[i] = *(const bf16x8*)&lds[(OAL + st) * 512 + lane * 8];
            }
#pragma unroll
            for (int j = 0; j < FN; ++j) {
                const int st = (wn * FN + j) * 2 + ks;
                bh[j] = *(const bf16x8*)&lds[(OBH + st) * 512 + lane * 8];
                if (BLO) bl[j] = *(const bf16x8*)&lds[(OBL + st) * 512 + lane * 8];
            }
#pragma unroll
            for (int i = 0; i < FM; ++i)
#pragma unroll
                for (int j = 0; j < FN; ++j) {
                    acc[i][j] = __builtin_amdgcn_mfma_f32_16x16x32_bf16(ah[i], bh[j], acc[i][j], 0, 0, 0);
                    if (BLO) acc[i][j] = __builtin_amdgcn_mfma_f32_16x16x32_bf16(ah[i], bl[j], acc[i][j], 0, 0, 0);
                    if (ALO) acc[i][j] = __builtin_amdgcn_mfma_f32_16x16x32_bf16(al[i], bh[j], acc[i][j], 0, 0, 0);
                }
        }
        __syncthreads();
    }

    const int fr = lane & 15, fc = lane >> 4;
#pragma unroll
    for (int i = 0; i < FM; ++i)
#pragma unroll
        for (int j = 0; j < FN; ++j) {
            const int mb = m0 + wm * FM * 16 + i * 16 + fc * 4;
            const int nb = n0 + wn * FN * 16 + j * 16 + fr;
            const float bv = bias ? bias[nb] : 0.f;
#pragma unroll
            for (int r = 0; r < 4; ++r) {
                const float v = acc[i][j][r] + bv;
                const size_t o = (size_t)(mb + r) * N + nb;
                if (Cf) Cf[o] = v;
                else if (Cbl) { const ushort hh = f2bf(v); Cbh[o] = hh; Cbl[o] = f2bf(v - bf2f(hh)); }
                else if (h16) Cbh[o] = f2h(v);
                else Cbh[o] = f2bf(v);
            }
        }
}

// ---------------- per-step kernels ----------------

// Issue for fp16 gates: 10 subtiles/iter: si 0-1 = hc16 (ks), 2-9 = Whh16 (gate,ks).
// Wave 0: si{0,1,2}, wave 1: {3,4,5}, wave 2: {6,7}, wave 3: {8,9}.
__device__ __forceinline__ void gc16_issue(
    const ushort* __restrict__ hc16, const ushort* __restrict__ Whh16,
    int jc, int mb, int wv, int lr, int lc, int k0, ushort* dst)
{
    const int base = (wv < 2) ? wv * 3 : 6 + (wv - 2) * 2;
    const int cnt  = (wv < 2) ? 3 : 2;
#pragma unroll
    for (int q = 0; q < 3; ++q) {
        if (q >= cnt) break;
        const int si = base + q;
        const ushort* P; size_t rowoff; int ks;
        if (si < 2) {
            P = hc16; ks = si;
            rowoff = (size_t)(mb * 16 + lr) * 1024;
        } else {
            P = Whh16;
            const int g = (si - 2) >> 1;
            ks = (si - 2) & 1;
            rowoff = (size_t)(g * 1024 + jc * 16 + lr) * 1024;
        }
        gll16(P + rowoff + k0 + ks * 32 + lc * 8, dst + si * 512);
    }
}

// K1: gates + LSTM cell, fp16 single-plane h and Whh (1-term MFMA).
// grid (64 colgrp, 4 batchgrp); wave g = gate g. 3-buffer pipeline, counted vmcnt.
__global__ __launch_bounds__(256) void gates_cell(
    const ushort* __restrict__ hc16, const ushort* __restrict__ Whh16,
    const float* __restrict__ xWt,
    float* __restrict__ c_buf, ushort* __restrict__ hy16)
{
    __shared__ ushort lds[3][5120];    // 30 KB
    __shared__ float gl[1024];         // 4 KB
    const int jc = blockIdx.x;
    const int mb = blockIdx.y;
    const int tid = threadIdx.x, lane = tid & 63, wv = tid >> 6;
    const int lr = lane & 15, lc = lane >> 4;

    f32x4 acc = (f32x4){0.f, 0.f, 0.f, 0.f};

    gc16_issue(hc16, Whh16, jc, mb, wv, lr, lc, 0, &lds[0][0]);
#pragma unroll
    for (int it = 0; it < 16; ++it) {
        if (it < 15) {
            gc16_issue(hc16, Whh16, jc, mb, wv, lr, lc,
                       (it + 1) * 64, &lds[(it + 1) % 3][0]);
            if (wv < 2) asm volatile("s_waitcnt vmcnt(3)" ::: "memory");
            else        asm volatile("s_waitcnt vmcnt(2)" ::: "memory");
        } else {
            asm volatile("s_waitcnt vmcnt(0)" ::: "memory");
        }
        __builtin_amdgcn_s_barrier();
        __builtin_amdgcn_sched_barrier(0);
        const ushort* L = &lds[it % 3][0];
#pragma unroll
        for (int ks = 0; ks < 2; ++ks) {
            f16x8 a = *(const f16x8*)&L[ks * 512 + lane * 8];
            f16x8 b = *(const f16x8*)&L[(2 + wv * 2 + ks) * 512 + lane * 8];
            acc = __builtin_amdgcn_mfma_f32_16x16x32_f16(a, b, acc, 0, 0, 0);
        }
    }

    const int fr = lane & 15, fc = lane >> 4;
#pragma unroll
    for (int r = 0; r < 4; ++r)
        gl[wv * 256 + (fc * 4 + r) * 16 + fr] = acc[r];
    __syncthreads();

    const int bl_ = tid >> 4, cl = tid & 15;
    const int b = mb * 16 + bl_, col = jc * 16 + cl;
    const float* xw = xWt + (size_t)b * T_ * 4096;
    const float gi = gl[bl_ * 16 + cl]        + xw[col];
    const float gf = gl[256 + bl_ * 16 + cl]  + xw[1024 + col];
    const float gg = gl[512 + bl_ * 16 + cl]  + xw[2048 + col];
    const float go = gl[768 + bl_ * 16 + cl]  + xw[3072 + col];
    const int idx = b * 1024 + col;
    const float cn = sigmoidf_(gf) * c_buf[idx] + sigmoidf_(gi) * tanhf(gg);
    c_buf[idx] = cn;
    const float h = sigmoidf_(go) * tanhf(cn);
    hy16[idx] = f2h(h);
}

// K2: raw scores from fp16 E and fp16 hy. grid (64 b, 4 sgroup of 32).
__global__ __launch_bounds__(256) void scores_k(
    const ushort* __restrict__ E,
    const ushort* __restrict__ hy16,
    const float* __restrict__ mask, float* __restrict__ sc_raw)
{
    const int b = blockIdx.x, sg = blockIdx.y;
    const int tid = threadIdx.x, lane = tid & 63, wv = tid >> 6;
    __shared__ alignas(16) float sinp[IN_];
#pragma unroll
    for (int i = 0; i < 4; ++i) {
        const int j = tid + i * 256;
        sinp[j] = h2f(hy16[b * 1024 + j]);
    }
    __syncthreads();
#pragma unroll
    for (int r = 0; r < 8; ++r) {
        const int s = sg * 32 + wv * 8 + r;
        const ushort* row = E + ((size_t)b * S_ + s) * 1024;
        float sum = 0.f;
#pragma unroll
        for (int it = 0; it < 2; ++it) {
            const int e = it * 512 + lane * 8;
            const uint4 v = *(const uint4*)(row + e);
            const float4 w0 = *(const float4*)&sinp[e];
            const float4 w1 = *(const float4*)&sinp[e + 4];
            sum += h2f(v.x & 0xffff) * w0.x + h2f(v.x >> 16) * w0.y
                 + h2f(v.y & 0xffff) * w0.z + h2f(v.y >> 16) * w0.w
                 + h2f(v.z & 0xffff) * w1.x + h2f(v.z >> 16) * w1.y
                 + h2f(v.w & 0xffff) * w1.z + h2f(v.w >> 16) * w1.w;
        }
#pragma unroll
        for (int off = 32; off > 0; off >>= 1) sum += __shfl_xor(sum, off);
        if (lane == 0)
            sc_raw[b * S_ + s] = sum - (1.0f - mask[(size_t)b * S_ + s]) * 100000.0f;
    }
}

// outg staging (fp16, 1-term): 4 subtiles/iter: hy ks0/ks1, Woi ks0/ks1.
__device__ __forceinline__ void og16_issue(
    const ushort* __restrict__ hy16, const ushort* __restrict__ Woi16,
    size_t arow, size_t brow, int kb, int it, int lc, ushort* dst)
{
    const int k0 = kb + it * 64 + lc * 8;
    gll16(hy16 + arow + k0,        dst);
    gll16(hy16 + arow + k0 + 32,   dst + 512);
    gll16(Woi16 + brow + k0,       dst + 1024);
    gll16(Woi16 + brow + k0 + 32,  dst + 1536);
}

// K3: out = tanh( softmax(sc) @ Gt + hy @ Woi^T ). grid (64 colgrp, 4 batchgrp).
// G-part: bf16 Gt stream. MFMA part: fp16 1-term, wave-private K-split dbuf.
__global__ __launch_bounds__(256) void outg_k(
    const float* __restrict__ sc_raw,
    const ushort* __restrict__ Gt_b,
    const ushort* __restrict__ hy16, const ushort* __restrict__ Woi16,
    float* __restrict__ outp, ushort* __restrict__ hc16)
{
    __shared__ ushort st[4][2][2048];   // 32 KB
    __shared__ float aS[16][128];       // 8 KB
    __shared__ float red[1024];         // 4 KB
    const int nc = blockIdx.x, mb = blockIdx.y;
    const int tid = threadIdx.x, lane = tid & 63, wv = tid >> 6;
    const int lr = lane & 15, lc = lane >> 4;
    const int kb = wv * 256;
    const size_t arow = (size_t)(mb * 16 + lr) * 1024;
    const size_t brow = (size_t)(nc * 16 + lr) * 1024;
    ushort* stw = &st[wv][0][0];

    og16_issue(hy16, Woi16, arow, brow, kb, 0, lc, stw);

    // softmax for this block's 16 batches (16 lanes per batch, in-wave)
    const int bl_ = tid >> 4, tl = tid & 15;
    const int b = mb * 16 + bl_;
    float v[8], mx = -3.4e38f;
#pragma unroll
    for (int i = 0; i < 8; ++i) {
        v[i] = sc_raw[b * S_ + tl * 8 + i];
        mx = fmaxf(mx, v[i]);
    }
#pragma unroll
    for (int off = 1; off < 16; off <<= 1) mx = fmaxf(mx, __shfl_xor(mx, off));
    float sm = 0.f;
#pragma unroll
    for (int i = 0; i < 8; ++i) { v[i] = expf(v[i] - mx); sm += v[i]; }
#pragma unroll
    for (int off = 1; off < 16; off <<= 1) sm += __shfl_xor(sm, off);
    const float inv = 1.0f / sm;
#pragma unroll
    for (int i = 0; i < 8; ++i) aS[bl_][tl * 8 + i] = v[i] * inv;
    asm volatile("s_waitcnt lgkmcnt(0)" ::: "memory");

    // G part: a @ Gt[b][col][:]  (Gt bf16 single plane)
    const int c = nc * 16 + tl;
    const ushort* gt = Gt_b + ((size_t)b * 1024 + c) * 128;
    float accg = 0.f;
#pragma unroll
    for (int i = 0; i < 16; ++i) {
        const uint4 g4 = *(const uint4*)(gt + i * 8);
        const float* a = &aS[bl_][i * 8];
        accg += a[0] * bf2f(g4.x & 0xffff) + a[1] * bf2f(g4.x >> 16)
              + a[2] * bf2f(g4.y & 0xffff) + a[3] * bf2f(g4.y >> 16)
              + a[4] * bf2f(g4.z & 0xffff) + a[5] * bf2f(g4.z >> 16)
              + a[6] * bf2f(g4.w & 0xffff) + a[7] * bf2f(g4.w >> 16);
    }

    // MFMA part: hy @ Woi^T (fp16 1-term), wave-private K slice, dbuf counted vmcnt
    asm volatile("s_waitcnt vmcnt(0)" ::: "memory");
    f32x4 acc = (f32x4){0.f, 0.f, 0.f, 0.f};
#pragma unroll
    for (int it = 0; it < 4; ++it) {
        if (it < 3) {
            og16_issue(hy16, Woi16, arow, brow, kb, it + 1, lc,
                       stw + ((it + 1) & 1) * 2048);
            asm volatile("s_waitcnt vmcnt(4)" ::: "memory");
        } else {
            asm volatile("s_waitcnt vmcnt(0)" ::: "memory");
        }
        __builtin_amdgcn_sched_barrier(0);
        const ushort* W = stw + (it & 1) * 2048;
#pragma unroll
        for (int ks = 0; ks < 2; ++ks) {
            f16x8 a = *(const f16x8*)&W[ks * 512 + lane * 8];
            f16x8 bb = *(const f16x8*)&W[(2 + ks) * 512 + lane * 8];
            acc = __builtin_amdgcn_mfma_f32_16x16x32_f16(a, bb, acc, 0, 0, 0);
        }
    }

    const int fc = lane >> 4, fr = lane & 15;
#pragma unroll
    for (int r = 0; r < 4; ++r)
        red[wv * 256 + (fc * 4 + r) * 16 + fr] = acc[r];
    __syncthreads();

    float o = accg + red[bl_ * 16 + tl] + red[256 + bl_ * 16 + tl]
            + red[512 + bl_ * 16 + tl] + red[768 + bl_ * 16 + tl];
    o = tanhf(o);
    outp[(size_t)b * T_ * 1024 + c] = o;
    hc16[b * 1024 + c] = f2h(o);
}

// ---------------- conversion / misc ----------------
__global__ __launch_bounds__(256) void cvt2_k(
    const float* __restrict__ in, ushort* __restrict__ hi, ushort* __restrict__ lo, int n4)
{
    const int i = blockIdx.x * 256 + threadIdx.x;
    if (i >= n4) return;
    const float4 v = ((const float4*)in)[i];
    ushort4 h, l;
    h.x = f2bf(v.x); l.x = f2bf(v.x - bf2f(h.x));
    h.y = f2bf(v.y); l.y = f2bf(v.y - bf2f(h.y));
    h.z = f2bf(v.z); l.z = f2bf(v.z - bf2f(h.z));
    h.w = f2bf(v.w); l.w = f2bf(v.w - bf2f(h.w));
    ((ushort4*)hi)[i] = h;
    ((ushort4*)lo)[i] = l;
}

__global__ __launch_bounds__(256) void cvt1_k(
    const float* __restrict__ in, ushort* __restrict__ hi, int n4)
{
    const int i = blockIdx.x * 256 + threadIdx.x;
    if (i >= n4) return;
    const float4 v = ((const float4*)in)[i];
    ushort4 h;
    h.x = f2bf(v.x); h.y = f2bf(v.y); h.z = f2bf(v.z); h.w = f2bf(v.w);
    ((ushort4*)hi)[i] = h;
}

__global__ __launch_bounds__(256) void cvt1h_k(
    const float* __restrict__ in, ushort* __restrict__ out, int n4)
{
    const int i = blockIdx.x * 256 + threadIdx.x;
    if (i >= n4) return;
    const float4 v = ((const float4*)in)[i];
    ushort4 h;
    h.x = f2h(v.x); h.y = f2h(v.y); h.z = f2h(v.z); h.w = f2h(v.w);
    ((ushort4*)out)[i] = h;
}

__global__ __launch_bounds__(256) void cvt2s_k(
    const float* __restrict__ in, long instride4, int rowlen4,
    ushort* __restrict__ hi, ushort* __restrict__ lo, int n4)
{
    const int i = blockIdx.x * 256 + threadIdx.x;
    if (i >= n4) return;
    const int r = i / rowlen4, c = i - r * rowlen4;
    const float4 v = ((const float4*)in)[(size_t)r * instride4 + c];
    ushort4 h, l;
    h.x = f2bf(v.x); l.x = f2bf(v.x - bf2f(h.x));
    h.y = f2bf(v.y); l.y = f2bf(v.y - bf2f(h.y));
    h.z = f2bf(v.z); l.z = f2bf(v.z - bf2f(h.z));
    h.w = f2bf(v.w); l.w = f2bf(v.w - bf2f(h.w));
    ((ushort4*)hi)[i] = h;
    ((ushort4*)lo)[i] = l;
}

__global__ void transpose_k(const float* __restrict__ in, float* __restrict__ out)
{
    __shared__ float tile[32][33];
    const int bx = blockIdx.x * 32, by = blockIdx.y * 32;
    const int tx = threadIdx.x, ty = threadIdx.y;   // (32,8)
#pragma unroll
    for (int i = 0; i < 32; i += 8)
        tile[ty + i][tx] = in[(size_t)(by + ty + i) * 1024 + bx + tx];
    __syncthreads();
#pragma unroll
    for (int i = 0; i < 32; i += 8)
        out[(size_t)(bx + ty + i) * 1024 + by + tx] = tile[tx][ty + i];
}

__global__ __launch_bounds__(256) void add_bias_k(
    const float* __restrict__ a, const float* __restrict__ b, float* __restrict__ o, int n)
{
    const int i = blockIdx.x * 256 + threadIdx.x;
    if (i < n) o[i] = a[i] + b[i];
}

__global__ __launch_bounds__(256) void finalize_k(
    const float* __restrict__ out_full, const float* __restrict__ c_buf,
    float* __restrict__ hT, float* __restrict__ cT)
{
    const int idx = blockIdx.x * 256 + threadIdx.x;
    const int b = idx >> 10, j = idx & 1023;
    hT[idx] = out_full[(size_t)b * T_ * H_ + (size_t)(T_ - 1) * H_ + j];
    cT[idx] = c_buf[idx];
}

extern "C" void kernel_launch(void* const* d_in, const int* in_sizes, int n_in,
                              void* d_out, int out_size, void* d_ws, size_t ws_size,
                              hipStream_t stream) {
    const float* target = (const float*)d_in[0];
    const float* h0     = (const float*)d_in[1];
    const float* c0     = (const float*)d_in[2];
    const float* ctx    = (const float*)d_in[3];
    const float* mask   = (const float*)d_in[4];
    const float* W_ih   = (const float*)d_in[5];
    const float* b_ih   = (const float*)d_in[6];
    const float* W_hh   = (const float*)d_in[7];
    const float* b_hh   = (const float*)d_in[8];
    const float* W_in   = (const float*)d_in[9];
    const float* W_ctx  = (const float*)d_in[10];
    const float* W_out  = (const float*)d_in[11];

    float* out = (float*)d_out;
    float* hT  = out + (size_t)B_ * T_ * H_;
    float* cT  = hT + (size_t)B_ * H_;

    // ---- workspace layout ----
    char* p = (char*)d_ws;
    ushort* E_h   = (ushort*)p;            p += 8388608ull * 2;    // 16.78 MB fp16
    float*  xW    = (float*)p;             p += 8388608ull * 4;    // 33.55 MB
    ushort* Gt_b  = (ushort*)p;            p += 8388608ull * 2;    // 16.78 MB bf16
    ushort* Whh16 = (ushort*)p;            p += 4194304ull * 2;    // 8.39 MB fp16
    ushort* Woi16 = (ushort*)p;            p += 1048576ull * 2;    // 2.10 MB fp16
    float*  bias_sum = (float*)p;          p += 4096ull * 4;
    float*  c_buf = (float*)p;             p += 65536ull * 4;
    ushort* hy16  = (ushort*)p;            p += 65536ull * 2;
    ushort* hc16  = (ushort*)p;            p += 65536ull * 2;
    float*  sc_raw = (float*)p;            p += 8192ull * 4;
    ushort* dcslot = (ushort*)p;           p += 8388608ull * 2;    // dc_b, later tgt planes
    ushort* trans  = (ushort*)p;           p += 20971520ull * 2;   // 41.9 MB transient

    ushort* dc_b   = dcslot;
    // transient phase A: ctx bf16 + W_ctx planes
    ushort* ctx_h  = trans;                            // 16,777,216
    ushort* Wctx_h = trans + 16777216;                 // 2,097,152
    ushort* Wctx_l = trans + 18874368;                 // 2,097,152
    // transient phase B: WinT_f + WinT + Wo1 + Wo2 planes
    float*  WinT_f = (float*)trans;
    ushort* WinT_h = trans + 2097152;
    ushort* WinT_l = trans + 3145728;
    ushort* Wo1_h  = trans + 4194304;
    ushort* Wo1_l  = trans + 5242880;
    ushort* Wo2_h  = trans + 6291456;
    ushort* Wo2_l  = trans + 7340032;
    // transient phase C: target planes (dc slot) + W_ih planes (trans)
    ushort* tgt_h  = dcslot;
    ushort* tgt_l  = dcslot + 2097152;
    ushort* Wih_h  = trans;
    ushort* Wih_l  = trans + 4194304;

    // ---- preamble ----
    add_bias_k<<<16, 256, 0, stream>>>(b_ih, b_hh, bias_sum, 4 * H_);
    cvt1h_k<<<4096, 256, 0, stream>>>(W_hh, Whh16, 1048576);

    // dense_ctx (bf16) = ctx @ W_ctx^T
    cvt1_k<<<16384, 256, 0, stream>>>(ctx, ctx_h, 4194304);
    cvt2_k<<<2048, 256, 0, stream>>>(W_ctx, Wctx_h, Wctx_l, 524288);
    gemm_bf<4, 4, false, true><<<dim3(8, 64), 256, 0, stream>>>(
        ctx_h, nullptr, 2048, Wctx_h, Wctx_l, 2048,
        2048, 1024, nullptr, dc_b, nullptr, nullptr, 0, 0, 0, 0);

    // WinT, Woi16 = Wo2@W_in (fp16), E = dc@W_in (fp16), Gt[b] = Wo1 @ dc[b]^T (bf16)
    transpose_k<<<dim3(32, 32), dim3(32, 8), 0, stream>>>(W_in, WinT_f);
    cvt2_k<<<1024, 256, 0, stream>>>(WinT_f, WinT_h, WinT_l, 262144);
    cvt2s_k<<<1024, 256, 0, stream>>>(W_out, 512, 256, Wo1_h, Wo1_l, 262144);
    cvt2s_k<<<1024, 256, 0, stream>>>(W_out + 1024, 512, 256, Wo2_h, Wo2_l, 262144);
    gemm_bf<4, 4, true, true><<<dim3(8, 8), 256, 0, stream>>>(
        Wo2_h, Wo2_l, 1024, WinT_h, WinT_l, 1024,
        1024, 1024, nullptr, Woi16, nullptr, nullptr, 0, 0, 0, 1);
    gemm_bf<4, 4, false, true><<<dim3(8, 64), 256, 0, stream>>>(
        dc_b, nullptr, 1024, WinT_h, WinT_l, 1024,
        1024, 1024, nullptr, E_h, nullptr, nullptr, 0, 0, 0, 1);
    gemm_bf<4, 4, true, false><<<dim3(1, 8, 64), 256, 0, stream>>>(
        Wo1_h, Wo1_l, 1024, dc_b, nullptr, 1024,
        1024, 128, nullptr, Gt_b, nullptr, nullptr, 0, 131072, 131072, 0);

    // xW = target @ W_ih^T + bias (dc dead now)
    cvt2_k<<<2048, 256, 0, stream>>>(target, tgt_h, tgt_l, 524288);
    cvt2_k<<<4096, 256, 0, stream>>>(W_ih, Wih_h, Wih_l, 1048576);
    gemm_bf<4, 4, true, true><<<dim3(32, 16), 256, 0, stream>>>(
        tgt_h, tgt_l, 1024, Wih_h, Wih_l, 1024,
        1024, 4096, xW, nullptr, nullptr, bias_sum, 0, 0, 0, 0);

    // loop state
    cvt1h_k<<<64, 256, 0, stream>>>(h0, hc16, 16384);
    hipMemcpyAsync(c_buf, c0, sizeof(float) * B_ * H_, hipMemcpyDeviceToDevice, stream);

    for (int t = 0; t < T_; ++t) {
        gates_cell<<<dim3(64, 4), 256, 0, stream>>>(
            hc16, Whh16, xW + (size_t)t * 4096, c_buf, hy16);
        scores_k<<<dim3(64, 4), 256, 0, stream>>>(E_h, hy16, mask, sc_raw);
        outg_k<<<dim3(64, 4), 256, 0, stream>>>(
            sc_raw, Gt_b, hy16, Woi16,
            out + (size_t)t * H_, hc16);
    }

    finalize_k<<<256, 256, 0, stream>>>(out, c_buf, hT, cT);
}

// Round 14
// 1039.524 us; speedup vs baseline: 3.2682x; 1.1214x over previous
//
#include <hip/hip_runtime.h>
#include <cstddef>

#define B_ 64
#define T_ 32
#define S_ 128
#define IN_ 1024
#define H_ 1024

typedef _Float16 f16x8 __attribute__((ext_vector_type(8)));
typedef float f32x4 __attribute__((ext_vector_type(4)));

__device__ __forceinline__ float sigmoidf_(float x) { return 1.0f / (1.0f + expf(-x)); }

__device__ __forceinline__ ushort f2h(float x) {
    return __builtin_bit_cast(ushort, (_Float16)x);
}
__device__ __forceinline__ float h2f(ushort h) {
    return (float)__builtin_bit_cast(_Float16, h);
}

// async global->LDS, 16B per lane; lds dest wave-uniform (HW adds lane*16).
__device__ __forceinline__ void gll16(const ushort* g, ushort* l) {
    __builtin_amdgcn_global_load_lds(
        (const __attribute__((address_space(1))) void*)g,
        (__attribute__((address_space(3))) void*)l,
        16, 0, 0);
}

// ---------------- fp16 big-GEMM (preamble): C = A @ B^T ----------------
// A,B fp16 single-plane. out: Cf -> fp32 (+bias), else Ch -> fp16.
// Optional z-batching via element strides Az/Bz/Cz. XCD swizzle when nwg%8==0.
template<int FM, int FN>
__global__ __launch_bounds__(256) void gemm_16(
    const ushort* __restrict__ A16, long lda,
    const ushort* __restrict__ B16, long ldb,
    int K, int N,
    float* __restrict__ Cf, ushort* __restrict__ Ch,
    const float* __restrict__ bias,
    long Az, long Bz, long Cz)
{
    constexpr int NSA = 4 * FM;
    constexpr int NSB = 4 * FN;
    constexpr int NST = NSA + NSB;
    __shared__ ushort lds[NST * 512];

    const long z = blockIdx.z;
    A16 += z * Az;
    B16 += z * Bz;
    if (Cf) Cf += z * Cz;
    if (Ch) Ch += z * Cz;

    int flat = blockIdx.y * gridDim.x + blockIdx.x;
    const int nwg = gridDim.x * gridDim.y;
    if ((nwg & 7) == 0) {
        const int q = nwg >> 3;
        flat = (flat & 7) * q + (flat >> 3);
    }
    const int bx = flat % gridDim.x;
    const int by = flat / gridDim.x;

    const int tid = threadIdx.x;
    const int lane = tid & 63, wv = tid >> 6;
    const int wm = wv >> 1, wn = wv & 1;
    const int m0 = by * (FM * 32), n0 = bx * (FN * 32);
    const int lr = lane & 15, lc = lane >> 4;

    f32x4 acc[FM][FN];
#pragma unroll
    for (int i = 0; i < FM; ++i)
#pragma unroll
        for (int j = 0; j < FN; ++j) acc[i][j] = (f32x4){0.f, 0.f, 0.f, 0.f};

    for (int k0 = 0; k0 < K; k0 += 64) {
#pragma unroll
        for (int q = 0; q < NST / 4; ++q) {
            const int si = wv * (NST / 4) + q;
            const ushort* P; long ld; int row0; int st;
            if (si < NSA) { P = A16; ld = lda; row0 = m0; st = si; }
            else          { P = B16; ld = ldb; row0 = n0; st = si - NSA; }
            const int row = ((st >> 1) << 4) + lr;
            const int kc = ((st & 1) << 5) + (lc << 3);
            gll16(P + (size_t)(row0 + row) * ld + k0 + kc, &lds[si * 512]);
        }
        __syncthreads();
#pragma unroll
        for (int ks = 0; ks < 2; ++ks) {
            f16x8 a[FM], b[FN];
#pragma unroll
            for (int i = 0; i < FM; ++i)
                a[i] = *(const f16x8*)&lds[((wm * FM + i) * 2 + ks) * 512 + lane * 8];
#pragma unroll
            for (int j = 0; j < FN; ++j)
                b[j] = *(const f16x8*)&lds[(NSA + (wn * FN + j) * 2 + ks) * 512 + lane * 8];
#pragma unroll
            for (int i = 0; i < FM; ++i)
#pragma unroll
                for (int j = 0; j < FN; ++j)
                    acc[i][j] = __builtin_amdgcn_mfma_f32_16x16x32_f16(a[i], b[j], acc[i][j], 0, 0, 0);
        }
        __syncthreads();
    }

    const int fr = lane & 15, fc = lane >> 4;
#pragma unroll
    for (int i = 0; i < FM; ++i)
#pragma unroll
        for (int j = 0; j < FN; ++j) {
            const int mb = m0 + wm * FM * 16 + i * 16 + fc * 4;
            const int nb = n0 + wn * FN * 16 + j * 16 + fr;
            const float bv = bias ? bias[nb] : 0.f;
#pragma unroll
            for (int r = 0; r < 4; ++r) {
                const float v = acc[i][j][r] + bv;
                const size_t o = (size_t)(mb + r) * N + nb;
                if (Cf) Cf[o] = v;
                else Ch[o] = f2h(v);
            }
        }
}

// ---------------- per-step kernels (round-13 proven) ----------------

// Issue for fp16 gates: 10 subtiles/iter: si 0-1 = hc16 (ks), 2-9 = Whh16 (gate,ks).
// Wave 0: si{0,1,2}, wave 1: {3,4,5}, wave 2: {6,7}, wave 3: {8,9}.
__device__ __forceinline__ void gc16_issue(
    const ushort* __restrict__ hc16, const ushort* __restrict__ Whh16,
    int jc, int mb, int wv, int lr, int lc, int k0, ushort* dst)
{
    const int base = (wv < 2) ? wv * 3 : 6 + (wv - 2) * 2;
    const int cnt  = (wv < 2) ? 3 : 2;
#pragma unroll
    for (int q = 0; q < 3; ++q) {
        if (q >= cnt) break;
        const int si = base + q;
        const ushort* P; size_t rowoff; int ks;
        if (si < 2) {
            P = hc16; ks = si;
            rowoff = (size_t)(mb * 16 + lr) * 1024;
        } else {
            P = Whh16;
            const int g = (si - 2) >> 1;
            ks = (si - 2) & 1;
            rowoff = (size_t)(g * 1024 + jc * 16 + lr) * 1024;
        }
        gll16(P + rowoff + k0 + ks * 32 + lc * 8, dst + si * 512);
    }
}

// K1: gates + LSTM cell, fp16 single-plane h and Whh (1-term MFMA).
// grid (64 colgrp, 4 batchgrp); wave g = gate g. 3-buffer pipeline, counted vmcnt.
__global__ __launch_bounds__(256) void gates_cell(
    const ushort* __restrict__ hc16, const ushort* __restrict__ Whh16,
    const float* __restrict__ xWt,
    float* __restrict__ c_buf, ushort* __restrict__ hy16)
{
    __shared__ ushort lds[3][5120];    // 30 KB
    __shared__ float gl[1024];         // 4 KB
    const int jc = blockIdx.x;
    const int mb = blockIdx.y;
    const int tid = threadIdx.x, lane = tid & 63, wv = tid >> 6;
    const int lr = lane & 15, lc = lane >> 4;

    f32x4 acc = (f32x4){0.f, 0.f, 0.f, 0.f};

    gc16_issue(hc16, Whh16, jc, mb, wv, lr, lc, 0, &lds[0][0]);
#pragma unroll
    for (int it = 0; it < 16; ++it) {
        if (it < 15) {
            gc16_issue(hc16, Whh16, jc, mb, wv, lr, lc,
                       (it + 1) * 64, &lds[(it + 1) % 3][0]);
            if (wv < 2) asm volatile("s_waitcnt vmcnt(3)" ::: "memory");
            else        asm volatile("s_waitcnt vmcnt(2)" ::: "memory");
        } else {
            asm volatile("s_waitcnt vmcnt(0)" ::: "memory");
        }
        __builtin_amdgcn_s_barrier();
        __builtin_amdgcn_sched_barrier(0);
        const ushort* L = &lds[it % 3][0];
#pragma unroll
        for (int ks = 0; ks < 2; ++ks) {
            f16x8 a = *(const f16x8*)&L[ks * 512 + lane * 8];
            f16x8 b = *(const f16x8*)&L[(2 + wv * 2 + ks) * 512 + lane * 8];
            acc = __builtin_amdgcn_mfma_f32_16x16x32_f16(a, b, acc, 0, 0, 0);
        }
    }

    const int fr = lane & 15, fc = lane >> 4;
#pragma unroll
    for (int r = 0; r < 4; ++r)
        gl[wv * 256 + (fc * 4 + r) * 16 + fr] = acc[r];
    __syncthreads();

    const int bl_ = tid >> 4, cl = tid & 15;
    const int b = mb * 16 + bl_, col = jc * 16 + cl;
    const float* xw = xWt + (size_t)b * T_ * 4096;
    const float gi = gl[bl_ * 16 + cl]        + xw[col];
    const float gf = gl[256 + bl_ * 16 + cl]  + xw[1024 + col];
    const float gg = gl[512 + bl_ * 16 + cl]  + xw[2048 + col];
    const float go = gl[768 + bl_ * 16 + cl]  + xw[3072 + col];
    const int idx = b * 1024 + col;
    const float cn = sigmoidf_(gf) * c_buf[idx] + sigmoidf_(gi) * tanhf(gg);
    c_buf[idx] = cn;
    const float h = sigmoidf_(go) * tanhf(cn);
    hy16[idx] = f2h(h);
}

// K2: raw scores from fp16 E and fp16 hy. grid (64 b, 4 sgroup of 32).
__global__ __launch_bounds__(256) void scores_k(
    const ushort* __restrict__ E,
    const ushort* __restrict__ hy16,
    const float* __restrict__ mask, float* __restrict__ sc_raw)
{
    const int b = blockIdx.x, sg = blockIdx.y;
    const int tid = threadIdx.x, lane = tid & 63, wv = tid >> 6;
    __shared__ alignas(16) float sinp[IN_];
#pragma unroll
    for (int i = 0; i < 4; ++i) {
        const int j = tid + i * 256;
        sinp[j] = h2f(hy16[b * 1024 + j]);
    }
    __syncthreads();
#pragma unroll
    for (int r = 0; r < 8; ++r) {
        const int s = sg * 32 + wv * 8 + r;
        const ushort* row = E + ((size_t)b * S_ + s) * 1024;
        float sum = 0.f;
#pragma unroll
        for (int it = 0; it < 2; ++it) {
            const int e = it * 512 + lane * 8;
            const uint4 v = *(const uint4*)(row + e);
            const float4 w0 = *(const float4*)&sinp[e];
            const float4 w1 = *(const float4*)&sinp[e + 4];
            sum += h2f(v.x & 0xffff) * w0.x + h2f(v.x >> 16) * w0.y
                 + h2f(v.y & 0xffff) * w0.z + h2f(v.y >> 16) * w0.w
                 + h2f(v.z & 0xffff) * w1.x + h2f(v.z >> 16) * w1.y
                 + h2f(v.w & 0xffff) * w1.z + h2f(v.w >> 16) * w1.w;
        }
#pragma unroll
        for (int off = 32; off > 0; off >>= 1) sum += __shfl_xor(sum, off);
        if (lane == 0)
            sc_raw[b * S_ + s] = sum - (1.0f - mask[(size_t)b * S_ + s]) * 100000.0f;
    }
}

// outg staging (fp16, 1-term): 4 subtiles/iter: hy ks0/ks1, Woi ks0/ks1.
__device__ __forceinline__ void og16_issue(
    const ushort* __restrict__ hy16, const ushort* __restrict__ Woi16,
    size_t arow, size_t brow, int kb, int it, int lc, ushort* dst)
{
    const int k0 = kb + it * 64 + lc * 8;
    gll16(hy16 + arow + k0,        dst);
    gll16(hy16 + arow + k0 + 32,   dst + 512);
    gll16(Woi16 + brow + k0,       dst + 1024);
    gll16(Woi16 + brow + k0 + 32,  dst + 1536);
}

// K3: out = tanh( softmax(sc) @ Gt + hy @ Woi^T ). grid (64 colgrp, 4 batchgrp).
// G-part: fp16 Gt stream. MFMA part: fp16 1-term, wave-private K-split dbuf.
__global__ __launch_bounds__(256) void outg_k(
    const float* __restrict__ sc_raw,
    const ushort* __restrict__ Gt16,
    const ushort* __restrict__ hy16, const ushort* __restrict__ Woi16,
    float* __restrict__ outp, ushort* __restrict__ hc16)
{
    __shared__ ushort st[4][2][2048];   // 32 KB
    __shared__ float aS[16][128];       // 8 KB
    __shared__ float red[1024];         // 4 KB
    const int nc = blockIdx.x, mb = blockIdx.y;
    const int tid = threadIdx.x, lane = tid & 63, wv = tid >> 6;
    const int lr = lane & 15, lc = lane >> 4;
    const int kb = wv * 256;
    const size_t arow = (size_t)(mb * 16 + lr) * 1024;
    const size_t brow = (size_t)(nc * 16 + lr) * 1024;
    ushort* stw = &st[wv][0][0];

    og16_issue(hy16, Woi16, arow, brow, kb, 0, lc, stw);

    // softmax for this block's 16 batches (16 lanes per batch, in-wave)
    const int bl_ = tid >> 4, tl = tid & 15;
    const int b = mb * 16 + bl_;
    float v[8], mx = -3.4e38f;
#pragma unroll
    for (int i = 0; i < 8; ++i) {
        v[i] = sc_raw[b * S_ + tl * 8 + i];
        mx = fmaxf(mx, v[i]);
    }
#pragma unroll
    for (int off = 1; off < 16; off <<= 1) mx = fmaxf(mx, __shfl_xor(mx, off));
    float sm = 0.f;
#pragma unroll
    for (int i = 0; i < 8; ++i) { v[i] = expf(v[i] - mx); sm += v[i]; }
#pragma unroll
    for (int off = 1; off < 16; off <<= 1) sm += __shfl_xor(sm, off);
    const float inv = 1.0f / sm;
#pragma unroll
    for (int i = 0; i < 8; ++i) aS[bl_][tl * 8 + i] = v[i] * inv;
    asm volatile("s_waitcnt lgkmcnt(0)" ::: "memory");

    // G part: a @ Gt[b][col][:]  (Gt fp16 single plane)
    const int c = nc * 16 + tl;
    const ushort* gt = Gt16 + ((size_t)b * 1024 + c) * 128;
    float accg = 0.f;
#pragma unroll
    for (int i = 0; i < 16; ++i) {
        const uint4 g4 = *(const uint4*)(gt + i * 8);
        const float* a = &aS[bl_][i * 8];
        accg += a[0] * h2f(g4.x & 0xffff) + a[1] * h2f(g4.x >> 16)
              + a[2] * h2f(g4.y & 0xffff) + a[3] * h2f(g4.y >> 16)
              + a[4] * h2f(g4.z & 0xffff) + a[5] * h2f(g4.z >> 16)
              + a[6] * h2f(g4.w & 0xffff) + a[7] * h2f(g4.w >> 16);
    }

    // MFMA part: hy @ Woi^T (fp16 1-term), wave-private K slice, dbuf counted vmcnt
    asm volatile("s_waitcnt vmcnt(0)" ::: "memory");
    f32x4 acc = (f32x4){0.f, 0.f, 0.f, 0.f};
#pragma unroll
    for (int it = 0; it < 4; ++it) {
        if (it < 3) {
            og16_issue(hy16, Woi16, arow, brow, kb, it + 1, lc,
                       stw + ((it + 1) & 1) * 2048);
            asm volatile("s_waitcnt vmcnt(4)" ::: "memory");
        } else {
            asm volatile("s_waitcnt vmcnt(0)" ::: "memory");
        }
        __builtin_amdgcn_sched_barrier(0);
        const ushort* W = stw + (it & 1) * 2048;
#pragma unroll
        for (int ks = 0; ks < 2; ++ks) {
            f16x8 a = *(const f16x8*)&W[ks * 512 + lane * 8];
            f16x8 bb = *(const f16x8*)&W[(2 + ks) * 512 + lane * 8];
            acc = __builtin_amdgcn_mfma_f32_16x16x32_f16(a, bb, acc, 0, 0, 0);
        }
    }

    const int fc = lane >> 4, fr = lane & 15;
#pragma unroll
    for (int r = 0; r < 4; ++r)
        red[wv * 256 + (fc * 4 + r) * 16 + fr] = acc[r];
    __syncthreads();

    float o = accg + red[bl_ * 16 + tl] + red[256 + bl_ * 16 + tl]
            + red[512 + bl_ * 16 + tl] + red[768 + bl_ * 16 + tl];
    o = tanhf(o);
    outp[(size_t)b * T_ * 1024 + c] = o;
    hc16[b * 1024 + c] = f2h(o);
}

// ---------------- conversion / misc ----------------
__global__ __launch_bounds__(256) void cvt1h_k(
    const float* __restrict__ in, ushort* __restrict__ out, int n4)
{
    const int i = blockIdx.x * 256 + threadIdx.x;
    if (i >= n4) return;
    const float4 v = ((const float4*)in)[i];
    ushort4 h;
    h.x = f2h(v.x); h.y = f2h(v.y); h.z = f2h(v.z); h.w = f2h(v.w);
    ((ushort4*)out)[i] = h;
}

// strided fp16 cvt: row r has rowlen4 float4s read from in + r*instride4 (float4 units)
__global__ __launch_bounds__(256) void cvt1hs_k(
    const float* __restrict__ in, long instride4, int rowlen4,
    ushort* __restrict__ out, int n4)
{
    const int i = blockIdx.x * 256 + threadIdx.x;
    if (i >= n4) return;
    const int r = i / rowlen4, c = i - r * rowlen4;
    const float4 v = ((const float4*)in)[(size_t)r * instride4 + c];
    ushort4 h;
    h.x = f2h(v.x); h.y = f2h(v.y); h.z = f2h(v.z); h.w = f2h(v.w);
    ((ushort4*)out)[i] = h;
}

__global__ void transpose_k(const float* __restrict__ in, float* __restrict__ out)
{
    __shared__ float tile[32][33];
    const int bx = blockIdx.x * 32, by = blockIdx.y * 32;
    const int tx = threadIdx.x, ty = threadIdx.y;   // (32,8)
#pragma unroll
    for (int i = 0; i < 32; i += 8)
        tile[ty + i][tx] = in[(size_t)(by + ty + i) * 1024 + bx + tx];
    __syncthreads();
#pragma unroll
    for (int i = 0; i < 32; i += 8)
        out[(size_t)(bx + ty + i) * 1024 + by + tx] = tile[tx][ty + i];
}

__global__ __launch_bounds__(256) void add_bias_k(
    const float* __restrict__ a, const float* __restrict__ b, float* __restrict__ o, int n)
{
    const int i = blockIdx.x * 256 + threadIdx.x;
    if (i < n) o[i] = a[i] + b[i];
}

__global__ __launch_bounds__(256) void finalize_k(
    const float* __restrict__ out_full, const float* __restrict__ c_buf,
    float* __restrict__ hT, float* __restrict__ cT)
{
    const int idx = blockIdx.x * 256 + threadIdx.x;
    const int b = idx >> 10, j = idx & 1023;
    hT[idx] = out_full[(size_t)b * T_ * H_ + (size_t)(T_ - 1) * H_ + j];
    cT[idx] = c_buf[idx];
}

extern "C" void kernel_launch(void* const* d_in, const int* in_sizes, int n_in,
                              void* d_out, int out_size, void* d_ws, size_t ws_size,
                              hipStream_t stream) {
    const float* target = (const float*)d_in[0];
    const float* h0     = (const float*)d_in[1];
    const float* c0     = (const float*)d_in[2];
    const float* ctx    = (const float*)d_in[3];
    const float* mask   = (const float*)d_in[4];
    const float* W_ih   = (const float*)d_in[5];
    const float* b_ih   = (const float*)d_in[6];
    const float* W_hh   = (const float*)d_in[7];
    const float* b_hh   = (const float*)d_in[8];
    const float* W_in   = (const float*)d_in[9];
    const float* W_ctx  = (const float*)d_in[10];
    const float* W_out  = (const float*)d_in[11];

    float* out = (float*)d_out;
    float* hT  = out + (size_t)B_ * T_ * H_;
    float* cT  = hT + (size_t)B_ * H_;

    // ---- workspace layout ----
    char* p = (char*)d_ws;
    ushort* E_h   = (ushort*)p;            p += 8388608ull * 2;    // 16.78 MB fp16
    float*  xW    = (float*)p;             p += 8388608ull * 4;    // 33.55 MB
    ushort* Gt16  = (ushort*)p;            p += 8388608ull * 2;    // 16.78 MB fp16
    ushort* Whh16 = (ushort*)p;            p += 4194304ull * 2;    // 8.39 MB fp16
    ushort* Woi16 = (ushort*)p;            p += 1048576ull * 2;    // 2.10 MB fp16
    float*  bias_sum = (float*)p;          p += 4096ull * 4;
    float*  c_buf = (float*)p;             p += 65536ull * 4;
    ushort* hy16  = (ushort*)p;            p += 65536ull * 2;
    ushort* hc16  = (ushort*)p;            p += 65536ull * 2;
    float*  sc_raw = (float*)p;            p += 8192ull * 4;
    ushort* dcslot = (ushort*)p;           p += 8388608ull * 2;    // dc16, later tgt16
    ushort* trans  = (ushort*)p;           p += 20971520ull * 2;   // 41.9 MB transient

    ushort* dc16   = dcslot;
    // transient phase A: ctx fp16 + W_ctx fp16
    ushort* ctx16  = trans;                            // 16,777,216
    ushort* Wctx16 = trans + 16777216;                 // 2,097,152
    // transient phase B: WinT_f + WinT16 + Wo1_16 + Wo2_16
    float*  WinT_f = (float*)trans;                    // 1,048,576 f (2,097,152 u-slots)
    ushort* WinT16 = trans + 2097152;
    ushort* Wo1_16 = trans + 3145728;
    ushort* Wo2_16 = trans + 4194304;
    // transient phase C: tgt16 (dc slot) + Wih16 (trans)
    ushort* tgt16  = dcslot;
    ushort* Wih16  = trans;

    // ---- preamble ----
    add_bias_k<<<16, 256, 0, stream>>>(b_ih, b_hh, bias_sum, 4 * H_);
    cvt1h_k<<<4096, 256, 0, stream>>>(W_hh, Whh16, 1048576);

    // dc16 = ctx @ W_ctx^T (fp16)
    cvt1h_k<<<16384, 256, 0, stream>>>(ctx, ctx16, 4194304);
    cvt1h_k<<<2048, 256, 0, stream>>>(W_ctx, Wctx16, 524288);
    gemm_16<4, 4><<<dim3(8, 64), 256, 0, stream>>>(
        ctx16, 2048, Wctx16, 2048, 2048, 1024,
        nullptr, dc16, nullptr, 0, 0, 0);

    // WinT, Woi16 = Wo2@W_in, E = dc@W_in (fp16), Gt[b] = Wo1 @ dc[b]^T (fp16)
    transpose_k<<<dim3(32, 32), dim3(32, 8), 0, stream>>>(W_in, WinT_f);
    cvt1h_k<<<1024, 256, 0, stream>>>(WinT_f, WinT16, 262144);
    cvt1hs_k<<<1024, 256, 0, stream>>>(W_out, 512, 256, Wo1_16, 262144);
    cvt1hs_k<<<1024, 256, 0, stream>>>(W_out + 1024, 512, 256, Wo2_16, 262144);
    gemm_16<4, 4><<<dim3(8, 8), 256, 0, stream>>>(
        Wo2_16, 1024, WinT16, 1024, 1024, 1024,
        nullptr, Woi16, nullptr, 0, 0, 0);
    gemm_16<4, 4><<<dim3(8, 64), 256, 0, stream>>>(
        dc16, 1024, WinT16, 1024, 1024, 1024,
        nullptr, E_h, nullptr, 0, 0, 0);
    gemm_16<4, 4><<<dim3(1, 8, 64), 256, 0, stream>>>(
        Wo1_16, 1024, dc16, 1024, 1024, 128,
        nullptr, Gt16, nullptr, 0, 131072, 131072);

    // xW = target @ W_ih^T + bias (dc dead now)
    cvt1h_k<<<2048, 256, 0, stream>>>(target, tgt16, 524288);
    cvt1h_k<<<4096, 256, 0, stream>>>(W_ih, Wih16, 1048576);
    gemm_16<4, 4><<<dim3(32, 16), 256, 0, stream>>>(
        tgt16, 1024, Wih16, 1024, 1024, 4096,
        xW, nullptr, bias_sum, 0, 0, 0);

    // loop state
    cvt1h_k<<<64, 256, 0, stream>>>(h0, hc16, 16384);
    hipMemcpyAsync(c_buf, c0, sizeof(float) * B_ * H_, hipMemcpyDeviceToDevice, stream);

    for (int t = 0; t < T_; ++t) {
        gates_cell<<<dim3(64, 4), 256, 0, stream>>>(
            hc16, Whh16, xW + (size_t)t * 4096, c_buf, hy16);
        scores_k<<<dim3(64, 4), 256, 0, stream>>>(E_h, hy16, mask, sc_raw);
        outg_k<<<dim3(64, 4), 256, 0, stream>>>(
            sc_raw, Gt16, hy16, Woi16,
            out + (size_t)t * H_, hc16);
    }

    finalize_k<<<256, 256, 0, stream>>>(out, c_buf, hT, cT);
}